// Round 7
// baseline (250.577 us; speedup 1.0000x reference)
//
#include <hip/hip_runtime.h>
#include <math.h>

#define SELU_SCALE 1.0507009873554804934193349852946f
#define SELU_ALPHA 1.6732632423543772848170429916717f

typedef short bf16x8 __attribute__((ext_vector_type(8)));
typedef float f32x4 __attribute__((ext_vector_type(4)));

__device__ __forceinline__ float selu_f(float x) {
    return SELU_SCALE * (x > 0.f ? x : SELU_ALPHA * expm1f(x));
}

__device__ __forceinline__ unsigned short f2bf(float f) {
    unsigned int u = __float_as_uint(f);
    u += 0x7FFF + ((u >> 16) & 1);  // round-to-nearest-even
    return (unsigned short)(u >> 16);
}
__device__ __forceinline__ float bflo(unsigned int u) { return __uint_as_float(u << 16); }
__device__ __forceinline__ float bfhi(unsigned int u) { return __uint_as_float(u & 0xFFFF0000u); }

__device__ __forceinline__ void acc8(float* a, uint4 v) {
    a[0] += bflo(v.x); a[1] += bfhi(v.x);
    a[2] += bflo(v.y); a[3] += bfhi(v.y);
    a[4] += bflo(v.z); a[5] += bfhi(v.z);
    a[6] += bflo(v.w); a[7] += bfhi(v.w);
}

__device__ __forceinline__ uint4 pack8(const float* a, float dv) {
    uint4 pk;
    pk.x = (unsigned int)f2bf(a[0] * dv) | ((unsigned int)f2bf(a[1] * dv) << 16);
    pk.y = (unsigned int)f2bf(a[2] * dv) | ((unsigned int)f2bf(a[3] * dv) << 16);
    pk.z = (unsigned int)f2bf(a[4] * dv) | ((unsigned int)f2bf(a[5] * dv) << 16);
    pk.w = (unsigned int)f2bf(a[6] * dv) | ((unsigned int)f2bf(a[7] * dv) << 16);
    return pk;
}

// ---------------------------------------------------------------------------
// prep: blocks 0..127 zero cnt; block 128 zeros hs1/hs2 sentinel rows;
// blocks 129..272 pack weights into MFMA B-fragment layout.
// Fragment f = nt*(K/32)+ks holds lane l elem j = W[ks*32+(l>>4)*8+j][nt*16+(l&15)].
// ---------------------------------------------------------------------------
__global__ __launch_bounds__(256) void prep_kernel(
    int* __restrict__ cnt, unsigned int* __restrict__ pad1,
    unsigned int* __restrict__ pad2,
    const float* __restrict__ W1, unsigned short* __restrict__ Wp1,
    const float* __restrict__ W2, unsigned short* __restrict__ Wp2) {
    int b = blockIdx.x;
    int t = threadIdx.x;
    if (b < 128) {
        cnt[b * 256 + t] = 0;
    } else if (b == 128) {
        if (t < 32) pad1[t] = 0;   // hs1 sentinel row (64 bf16)
        if (t < 64) pad2[t] = 0;   // hs2 sentinel row (128 bf16)
    } else {
        if (t >= 64) return;
        int fb = b - 129;
        const float* W; unsigned short* Wp; int K, N, f;
        if (fb < 16) { W = W1; Wp = Wp1; K = 64; N = 128; f = fb; }
        else         { W = W2; Wp = Wp2; K = 128; N = 512; f = fb - 16; }
        int l = t;  // 0..63
        int KS = K / 32;
        int nt = f / KS, ks = f % KS;
        int ncol = nt * 16 + (l & 15);
        int k0 = ks * 32 + (l >> 4) * 8;
        unsigned short v[8];
        #pragma unroll
        for (int j = 0; j < 8; j++) v[j] = f2bf(W[(size_t)(k0 + j) * N + ncol]);
        *(uint4*)&Wp[((size_t)f * 64 + l) * 8] = *(uint4*)v;
    }
}

// count degrees AND record each edge's slot within its destination's segment
__global__ void count_kernel(const int* __restrict__ dst, int* __restrict__ cnt,
                             int* __restrict__ epos, int E) {
    int e = blockIdx.x * blockDim.x + threadIdx.x;
    if (e < E) epos[e] = atomicAdd(&cnt[dst[e]], 1);
}

// --- parallel exclusive scan over padded counts ((c+7)&~7) ---
// A: per-block sums + dinv
__global__ __launch_bounds__(256) void scanA_kernel(const int* __restrict__ cnt,
                                                    int* __restrict__ blockSums,
                                                    float* __restrict__ dinv) {
    __shared__ int red[256];
    int t = threadIdx.x;
    int i = blockIdx.x * 256 + t;
    int c = cnt[i];
    dinv[i] = rsqrtf((float)(c + 1));
    red[t] = (c + 7) & ~7;
    __syncthreads();
    for (int s = 128; s > 0; s >>= 1) {
        if (t < s) red[t] += red[t + s];
        __syncthreads();
    }
    if (t == 0) blockSums[blockIdx.x] = red[0];
}

// C: block-local scan + inline scan of the 128 block sums -> indptr,
// sentinel pad-fill of ssrc
__global__ __launch_bounds__(256) void scanC_kernel(
    const int* __restrict__ cnt, const int* __restrict__ bsums,
    int* __restrict__ indptr, int* __restrict__ ssrc, int n) {
    __shared__ int sc[256];
    __shared__ int bs[128];
    int t = threadIdx.x;
    int ownSum = bsums[blockIdx.x];
    if (t < 128) bs[t] = bsums[t];
    int i = blockIdx.x * 256 + t;
    int c = cnt[i];
    int pc = (c + 7) & ~7;
    sc[t] = pc;
    __syncthreads();
    for (int off = 1; off < 128; off <<= 1) {
        int v = (t >= off && t < 128) ? bs[t - off] : 0;
        __syncthreads();
        if (t < 128) bs[t] += v;
        __syncthreads();
    }
    for (int off = 1; off < 256; off <<= 1) {
        int v = t >= off ? sc[t - off] : 0;
        __syncthreads();
        sc[t] += v;
        __syncthreads();
    }
    int blockOff = bs[blockIdx.x] - ownSum;  // exclusive block offset
    int ip = blockOff + sc[t] - pc;          // exclusive elem offset
    indptr[i] = ip;
    for (int k = c; k < pc; k++) ssrc[ip + k] = n;  // sentinel zero-row
    if (i == n - 1) indptr[n] = blockOff + sc[t];
}

// ---------------------------------------------------------------------------
// scatter (blocks 0..nb_scatter-1) || cov_enc (remaining 128 blocks).
// scatter: atomic-free using recorded positions.
// cov_enc: local covariance (window 25, div 23) + [x,cov]@w_e1+b_e1, selu,
// prescaled by dinv, stored bf16.
// ---------------------------------------------------------------------------
__global__ __launch_bounds__(256) void scatter_cov_kernel(
    const int* __restrict__ src, const int* __restrict__ dst,
    const int* __restrict__ epos, const int* __restrict__ indptr,
    int* __restrict__ ssrc, int E, int nb_scatter,
    const float* __restrict__ x, const float* __restrict__ w_e1,
    const float* __restrict__ b_e1, const float* __restrict__ dinv,
    unsigned short* __restrict__ hs1) {
    int t = threadIdx.x;
    if ((int)blockIdx.x < nb_scatter) {
        int e = blockIdx.x * 256 + t;
        if (e < E) ssrc[indptr[dst[e]] + epos[e]] = src[e];
        return;
    }
    // ---- cov_enc part ----
    __shared__ float Wl[12 * 64];
    __shared__ float Bl[64];
    __shared__ float xs[280 * 3];
    int cb = blockIdx.x - nb_scatter;  // 0..127
    for (int i = t; i < 768; i += 256) Wl[i] = w_e1[i];
    if (t < 64) Bl[t] = b_e1[t];
    int p0 = cb * 256;
    int n0 = p0 & 4095;
    const float* xb = x + (size_t)(p0 - n0) * 3;  // batch base (256 | 4096)
    for (int idx = t; idx < 840; idx += 256) {
        int slot = idx / 3, d = idx - slot * 3;
        int g = n0 - 12 + slot;
        g = g < 0 ? 0 : (g > 4095 ? 4095 : g);
        xs[idx] = xb[g * 3 + d];
    }
    __syncthreads();
    int p = p0 + t;
    int n = n0 + t;
    int lo = n - 12 < 0 ? 0 : n - 12;
    int hi = n + 12 > 4095 ? 4095 : n + 12;
    int slo = lo - n0 + 12, shi = hi - n0 + 12;
    float sx = 0.f, sy = 0.f, sz = 0.f;
    float sxx = 0.f, sxy = 0.f, sxz = 0.f, syy = 0.f, syz = 0.f, szz = 0.f;
    for (int s = slo; s <= shi; s++) {
        float xv = xs[s * 3 + 0], yv = xs[s * 3 + 1], zv = xs[s * 3 + 2];
        sx += xv; sy += yv; sz += zv;
        sxx = fmaf(xv, xv, sxx); sxy = fmaf(xv, yv, sxy); sxz = fmaf(xv, zv, sxz);
        syy = fmaf(yv, yv, syy); syz = fmaf(yv, zv, syz); szz = fmaf(zv, zv, szz);
    }
    float cntf = (float)(shi - slo + 1);
    float rin = 1.f / cntf;
    float mx = sx * rin, my = sy * rin, mz = sz * rin;
    const float inv23 = 1.f / 23.f;
    float c00 = (sxx - sx * mx) * inv23;
    float c01 = (sxy - sx * my) * inv23;
    float c02 = (sxz - sx * mz) * inv23;
    float c11 = (syy - sy * my) * inv23;
    float c12 = (syz - sy * mz) * inv23;
    float c22 = (szz - sz * mz) * inv23;
    float feat[12];
    feat[0] = xs[(t + 12) * 3 + 0];
    feat[1] = xs[(t + 12) * 3 + 1];
    feat[2] = xs[(t + 12) * 3 + 2];
    feat[3] = c00; feat[4] = c01; feat[5]  = c02;
    feat[6] = c01; feat[7] = c11; feat[8]  = c12;
    feat[9] = c02; feat[10] = c12; feat[11] = c22;
    float dv = dinv[p];
    unsigned int* hp = (unsigned int*)(hs1 + (size_t)p * 64);
    for (int c = 0; c < 64; c += 2) {
        float a0 = Bl[c], a1 = Bl[c + 1];
        #pragma unroll
        for (int i = 0; i < 12; i++) {
            a0 = fmaf(feat[i], Wl[i * 64 + c], a0);
            a1 = fmaf(feat[i], Wl[i * 64 + c + 1], a1);
        }
        unsigned int pk = (unsigned int)f2bf(dv * selu_f(a0)) |
                          ((unsigned int)f2bf(dv * selu_f(a1)) << 16);
        hp[c >> 1] = pk;
    }
}

// ---------------------------------------------------------------------------
// Fused GCN1: per block, aggregate 128 nodes (C=64) straight into the MFMA
// LDS A-buffer, then gemm vs Wp1 (K=64, N=128) and write bf16 hs2
// (dinv-prescaled).
// ---------------------------------------------------------------------------
__global__ __launch_bounds__(256) void gcn1_kernel(
    const unsigned short* __restrict__ hs1, const float* __restrict__ dinv,
    const int* __restrict__ indptr, const int* __restrict__ ssrc,
    const unsigned short* __restrict__ Wp, const float* __restrict__ bias,
    unsigned short* __restrict__ hs2) {
    constexpr int LDA = 72;  // 64 + 8 bf16 pad
    __shared__ unsigned short As[128 * LDA];
    int t = threadIdx.x;
    int R0 = blockIdx.x * 128;
    const uint4* hp = (const uint4*)hs1;

    // aggregation phase: 128 nodes x 8 uint4-chunks = 1024 tasks
    for (int idx = t; idx < 1024; idx += 256) {
        int nl = idx >> 3, cq = idx & 7;
        int node = R0 + nl;
        float a[8];
        {
            uint4 u = hp[(size_t)node * 8 + cq];
            a[0] = bflo(u.x); a[1] = bfhi(u.x);
            a[2] = bflo(u.y); a[3] = bfhi(u.y);
            a[4] = bflo(u.z); a[5] = bfhi(u.z);
            a[6] = bflo(u.w); a[7] = bfhi(u.w);
        }
        int beg = indptr[node], end = indptr[node + 1];
        for (int j = beg; j < end; j += 8) {
            int s[8];
            #pragma unroll
            for (int q = 0; q < 8; q++) s[q] = ssrc[j + q];
            uint4 v[8];
            #pragma unroll
            for (int q = 0; q < 8; q++) v[q] = hp[(size_t)s[q] * 8 + cq];
            #pragma unroll
            for (int q = 0; q < 8; q++) acc8(a, v[q]);
        }
        *(uint4*)&As[nl * LDA + cq * 8] = pack8(a, dinv[node]);
    }
    __syncthreads();

    // gemm phase: K=64 (KS=2), N=128, epilogue dinv*selu -> bf16 hs2
    int wave = t >> 6, l = t & 63;
    int ml = l & 15, q = l >> 4;
    int wr = wave * 32;
    f32x4 acc[2][8];
    #pragma unroll
    for (int mf = 0; mf < 2; mf++)
        #pragma unroll
        for (int nf = 0; nf < 8; nf++) acc[mf][nf] = (f32x4){0.f, 0.f, 0.f, 0.f};
    const bf16x8* wp8 = (const bf16x8*)Wp;
    #pragma unroll
    for (int ks = 0; ks < 2; ks++) {
        bf16x8 af[2];
        #pragma unroll
        for (int mf = 0; mf < 2; mf++)
            af[mf] = *(const bf16x8*)&As[(wr + mf * 16 + ml) * LDA + ks * 32 + q * 8];
        bf16x8 bfr[8];
        #pragma unroll
        for (int nf = 0; nf < 8; nf++)
            bfr[nf] = wp8[(size_t)(nf * 2 + ks) * 64 + l];
        #pragma unroll
        for (int mf = 0; mf < 2; mf++)
            #pragma unroll
            for (int nf = 0; nf < 8; nf++)
                acc[mf][nf] = __builtin_amdgcn_mfma_f32_16x16x32_bf16(
                    af[mf], bfr[nf], acc[mf][nf], 0, 0, 0);
    }
    float bj[8];
    #pragma unroll
    for (int nf = 0; nf < 8; nf++) bj[nf] = bias[nf * 16 + ml];
    #pragma unroll
    for (int mf = 0; mf < 2; mf++) {
        #pragma unroll
        for (int r = 0; r < 4; r++) {
            int row = R0 + wr + mf * 16 + q * 4 + r;
            float dv = dinv[row];
            #pragma unroll
            for (int nf = 0; nf < 8; nf++) {
                float v = dv * selu_f(acc[mf][nf][r] + bj[nf]);
                hs2[(size_t)row * 128 + nf * 16 + ml] = f2bf(v);
            }
        }
    }
}

// ---------------------------------------------------------------------------
// Fused GCN2: 64 rows x 512 cols per block (512 blocks).
// Phase 1: aggregate 64 nodes (C=128) into LDS A-buffer, channel-phased
// (ch 0..63 for all nodes, then 64..127) to halve the L2 gather working set.
// Phase 2: MFMA K=128 vs Wp2 (global, L2-resident), selu + column max -> pmax.
// Each wave: 16 rows x 512 cols (acc = 32 f32x4).
// ---------------------------------------------------------------------------
__global__ __launch_bounds__(256, 2) void gcn2_kernel(
    const unsigned short* __restrict__ hs2, const float* __restrict__ dinv,
    const int* __restrict__ indptr, const int* __restrict__ ssrc,
    const unsigned short* __restrict__ Wp, const float* __restrict__ bias,
    float* __restrict__ pmax) {
    constexpr int LDA = 136;  // 128 + 8 bf16 pad
    __shared__ unsigned short As[64 * LDA];
    int t = threadIdx.x;
    int R0 = blockIdx.x * 64;
    const uint4* hp = (const uint4*)hs2;

    // aggregation: 2 halves x 64 nodes x 8 uint4-chunks = 1024 tasks,
    // ordered so低 channels complete for all nodes before high channels.
    #pragma unroll
    for (int it = 0; it < 4; it++) {
        int idx = it * 256 + t;
        int half = idx >> 9;
        int j9 = idx & 511;
        int nl = j9 >> 3;
        int cq = (half << 3) | (j9 & 7);  // 0..15
        int node = R0 + nl;
        float a[8];
        {
            uint4 u = hp[(size_t)node * 16 + cq];
            a[0] = bflo(u.x); a[1] = bfhi(u.x);
            a[2] = bflo(u.y); a[3] = bfhi(u.y);
            a[4] = bflo(u.z); a[5] = bfhi(u.z);
            a[6] = bflo(u.w); a[7] = bfhi(u.w);
        }
        int beg = indptr[node], end = indptr[node + 1];
        for (int j = beg; j < end; j += 8) {
            int s[8];
            #pragma unroll
            for (int q = 0; q < 8; q++) s[q] = ssrc[j + q];
            uint4 v[8];
            #pragma unroll
            for (int q = 0; q < 8; q++) v[q] = hp[(size_t)s[q] * 16 + cq];
            #pragma unroll
            for (int q = 0; q < 8; q++) acc8(a, v[q]);
        }
        *(uint4*)&As[nl * LDA + cq * 8] = pack8(a, dinv[node]);
    }
    __syncthreads();

    // gemm: each wave does rows wr..wr+15, all 512 cols
    int wave = t >> 6, l = t & 63;
    int ml = l & 15, q = l >> 4;
    int wr = wave * 16;
    f32x4 acc[32];
    #pragma unroll
    for (int nf = 0; nf < 32; nf++) acc[nf] = (f32x4){0.f, 0.f, 0.f, 0.f};
    const bf16x8* wp8 = (const bf16x8*)Wp;
    #pragma unroll
    for (int ks = 0; ks < 4; ks++) {
        bf16x8 af = *(const bf16x8*)&As[(wr + ml) * LDA + ks * 32 + q * 8];
        #pragma unroll
        for (int nf = 0; nf < 32; nf++) {
            bf16x8 bfr = wp8[(size_t)(nf * 4 + ks) * 64 + l];
            acc[nf] = __builtin_amdgcn_mfma_f32_16x16x32_bf16(af, bfr, acc[nf], 0, 0, 0);
        }
    }

    // selu + column max over the wave's 16 rows; C/D: col=ml, row=q*4+r
    float cmax[32];
    #pragma unroll
    for (int nf = 0; nf < 32; nf++) {
        float bj = bias[nf * 16 + ml];
        float v = -INFINITY;
        #pragma unroll
        for (int r = 0; r < 4; r++) v = fmaxf(v, selu_f(acc[nf][r] + bj));
        v = fmaxf(v, __shfl_xor(v, 16, 64));
        v = fmaxf(v, __shfl_xor(v, 32, 64));
        cmax[nf] = v;
    }
    __syncthreads();  // before reusing As as f32 scratch
    float* redf = (float*)As;  // [4 waves][512 cols] = 8 KB
    if (l < 16) {
        #pragma unroll
        for (int nf = 0; nf < 32; nf++) redf[wave * 512 + nf * 16 + l] = cmax[nf];
    }
    __syncthreads();
    #pragma unroll
    for (int cc = 0; cc < 2; cc++) {
        int c = cc * 256 + t;
        float v = redf[c];
        v = fmaxf(v, redf[512 + c]);
        v = fmaxf(v, redf[1024 + c]);
        v = fmaxf(v, redf[1536 + c]);
        pmax[(size_t)blockIdx.x * 512 + c] = v;
    }
}

// ---------------------------------------------------------------------------
// lat: m[b][c] = max over 64 pmax tiles; lat = selu(m @ w_e2 + b_e2);
// latw1 = lat @ w_d1[:512] + b_d1; latw2 = lat @ w_d2[:512] + b_d2.
// ---------------------------------------------------------------------------
__global__ __launch_bounds__(256) void lat_kernel(
    const float* __restrict__ pmax, const float* __restrict__ w_e2,
    const float* __restrict__ b_e2, const float* __restrict__ w_d1,
    const float* __restrict__ b_d1, const float* __restrict__ w_d2,
    const float* __restrict__ b_d2, float* __restrict__ latw1,
    float* __restrict__ latw2) {
    int b = blockIdx.x;
    int t = threadIdx.x;
    __shared__ float ml[512], ll[512];
    __shared__ float red[6][256];
    for (int c = t; c < 512; c += 256) {
        const float* p = pmax + (size_t)(b * 64) * 512 + c;
        float v = -INFINITY;
        #pragma unroll
        for (int k = 0; k < 64; k++) v = fmaxf(v, p[k * 512]);
        ml[c] = v;
    }
    __syncthreads();
    for (int cc = 0; cc < 2; cc++) {
        int c = t + cc * 256;
        float acc = b_e2[c];
        for (int k = 0; k < 512; k++) acc = fmaf(ml[k], w_e2[k * 512 + c], acc);
        ll[c] = selu_f(acc);
    }
    __syncthreads();
    float p[6] = {0.f, 0.f, 0.f, 0.f, 0.f, 0.f};
    for (int k = t; k < 512; k += 256) {
        float lv = ll[k];
        #pragma unroll
        for (int j = 0; j < 3; j++) {
            p[j]     = fmaf(lv, w_d1[k * 3 + j], p[j]);
            p[3 + j] = fmaf(lv, w_d2[k * 3 + j], p[3 + j]);
        }
    }
    #pragma unroll
    for (int j = 0; j < 6; j++) red[j][t] = p[j];
    __syncthreads();
    for (int s = 128; s > 0; s >>= 1) {
        if (t < s) {
            #pragma unroll
            for (int j = 0; j < 6; j++) red[j][t] += red[j][t + s];
        }
        __syncthreads();
    }
    if (t < 3) {
        latw1[b * 3 + t] = red[t][0] + b_d1[t];
        latw2[b * 3 + t] = red[3 + t][0] + b_d2[t];
    }
}

// ---------------------------------------------------------------------------
// decoder: per point, grid coords + two 3-wide folds
// ---------------------------------------------------------------------------
__global__ void decode_kernel(const float* __restrict__ latw1, const float* __restrict__ latw2,
                              const float* __restrict__ w_d1, const float* __restrict__ w_d2,
                              float* __restrict__ out, int total) {
    int p = blockIdx.x * blockDim.x + threadIdx.x;
    if (p >= total) return;
    int b = p >> 12;
    int n = p & 4095;
    int i = n / 46;
    int j = n - i * 46;
    float y0 = fmaf((float)i, 119.f / 90.f, 1.f);
    float y1 = fmaf((float)j, 59.f / 45.f, 1.f);
    float k0 = selu_f(latw1[b * 3 + 0] + y0 * w_d1[1536 + 0] + y1 * w_d1[1539 + 0]);
    float k1 = selu_f(latw1[b * 3 + 1] + y0 * w_d1[1536 + 1] + y1 * w_d1[1539 + 1]);
    float k2 = selu_f(latw1[b * 3 + 2] + y0 * w_d1[1536 + 2] + y1 * w_d1[1539 + 2]);
    float o0 = selu_f(latw2[b * 3 + 0] + k0 * w_d2[1536 + 0] + k1 * w_d2[1539 + 0] + k2 * w_d2[1542 + 0]);
    float o1 = selu_f(latw2[b * 3 + 1] + k0 * w_d2[1536 + 1] + k1 * w_d2[1539 + 1] + k2 * w_d2[1542 + 1]);
    float o2 = selu_f(latw2[b * 3 + 2] + k0 * w_d2[1536 + 2] + k1 * w_d2[1539 + 2] + k2 * w_d2[1542 + 2]);
    out[(size_t)p * 3 + 0] = o0;
    out[(size_t)p * 3 + 1] = o1;
    out[(size_t)p * 3 + 2] = o2;
}

// ---------------------------------------------------------------------------
extern "C" void kernel_launch(void* const* d_in, const int* in_sizes, int n_in,
                              void* d_out, int out_size, void* d_ws, size_t ws_size,
                              hipStream_t stream) {
    const float* x    = (const float*)d_in[0];
    const int*   knn  = (const int*)d_in[1];
    const float* w_e1 = (const float*)d_in[2];
    const float* b_e1 = (const float*)d_in[3];
    const float* w_g1 = (const float*)d_in[4];
    const float* b_g1 = (const float*)d_in[5];
    const float* w_g2 = (const float*)d_in[6];
    const float* b_g2 = (const float*)d_in[7];
    const float* w_e2 = (const float*)d_in[8];
    const float* b_e2 = (const float*)d_in[9];
    const float* w_d1 = (const float*)d_in[10];
    const float* b_d1 = (const float*)d_in[11];
    const float* w_d2 = (const float*)d_in[12];
    const float* b_d2 = (const float*)d_in[13];
    float* out = (float*)d_out;

    const int BN = in_sizes[0] / 3;   // 32768
    const int E  = in_sizes[1] / 2;   // 524288
    const int Bb = BN / 4096;         // 8
    const int* src = knn;
    const int* dst = knn + E;

    size_t off = 0;
    auto alloc = [&](size_t bytes) -> void* {
        void* p = (char*)d_ws + off;
        off += (bytes + 255) & ~(size_t)255;
        return p;
    };
    unsigned short* hs1 = (unsigned short*)alloc((size_t)(BN + 1) * 64 * 2);
    unsigned short* hs2 = (unsigned short*)alloc((size_t)(BN + 1) * 128 * 2);
    unsigned short* Wp1 = (unsigned short*)alloc((size_t)16 * 64 * 8 * 2);
    unsigned short* Wp2 = (unsigned short*)alloc((size_t)128 * 64 * 8 * 2);
    float* pmax   = (float*)alloc((size_t)(BN / 64) * 512 * 4);
    float* latw1  = (float*)alloc((size_t)Bb * 3 * 4);
    float* latw2  = (float*)alloc((size_t)Bb * 3 * 4);
    float* dinv   = (float*)alloc((size_t)BN * 4);
    int*   cnt    = (int*)alloc((size_t)BN * 4);
    int*   epos   = (int*)alloc((size_t)E * 4);
    int*   indptr = (int*)alloc((size_t)(BN + 1) * 4);
    int*   bsums  = (int*)alloc((size_t)128 * 4);
    int*   ssrc   = (int*)alloc((size_t)(E + 7 * BN + 1024) * 4);
    (void)ws_size;

    const int nb_scatter = (E + 255) / 256;  // 2048

    // prep: zero cnt + sentinel rows, pack both weight matrices
    prep_kernel<<<273, 256, 0, stream>>>(
        cnt, (unsigned int*)(hs1 + (size_t)BN * 64),
        (unsigned int*)(hs2 + (size_t)BN * 128), w_g1, Wp1, w_g2, Wp2);
    // count + per-edge slot
    count_kernel<<<(E + 255) / 256, 256, 0, stream>>>(dst, cnt, epos, E);
    scanA_kernel<<<BN / 256, 256, 0, stream>>>(cnt, bsums, dinv);
    scanC_kernel<<<BN / 256, 256, 0, stream>>>(cnt, bsums, indptr, ssrc, BN);
    // scatter || encoder (independent after scanA/scanC)
    scatter_cov_kernel<<<nb_scatter + 128, 256, 0, stream>>>(
        src, dst, epos, indptr, ssrc, E, nb_scatter,
        x, w_e1, b_e1, dinv, hs1);

    // GCN1 fused: agg(64) -> MFMA K=64 -> bf16 hs2 (dinv-prescaled)
    gcn1_kernel<<<BN / 128, 256, 0, stream>>>(hs1, dinv, indptr, ssrc, Wp1, b_g1, hs2);

    // GCN2 fused: agg(128, channel-phased) -> MFMA K=128 + selu + column max
    gcn2_kernel<<<BN / 64, 256, 0, stream>>>(hs2, dinv, indptr, ssrc, Wp2, b_g2, pmax);

    // max-pool + latent + per-batch decoder coefficients (fused)
    lat_kernel<<<Bb, 256, 0, stream>>>(pmax, w_e2, b_e2, w_d1, b_d1, w_d2, b_d2, latw1, latw2);

    // decoder
    decode_kernel<<<(BN + 255) / 256, 256, 0, stream>>>(latw1, latw2, w_d1, w_d2, out, BN);
}

// Round 8
// 238.052 us; speedup vs baseline: 1.0526x; 1.0526x over previous
//
#include <hip/hip_runtime.h>
#include <math.h>

#define SELU_SCALE 1.0507009873554804934193349852946f
#define SELU_ALPHA 1.6732632423543772848170429916717f

typedef short bf16x8 __attribute__((ext_vector_type(8)));
typedef float f32x4 __attribute__((ext_vector_type(4)));

__device__ __forceinline__ float selu_f(float x) {
    return SELU_SCALE * (x > 0.f ? x : SELU_ALPHA * expm1f(x));
}

__device__ __forceinline__ unsigned short f2bf(float f) {
    unsigned int u = __float_as_uint(f);
    u += 0x7FFF + ((u >> 16) & 1);  // round-to-nearest-even
    return (unsigned short)(u >> 16);
}
__device__ __forceinline__ float bflo(unsigned int u) { return __uint_as_float(u << 16); }
__device__ __forceinline__ float bfhi(unsigned int u) { return __uint_as_float(u & 0xFFFF0000u); }

__device__ __forceinline__ void acc8(float* a, uint4 v) {
    a[0] += bflo(v.x); a[1] += bfhi(v.x);
    a[2] += bflo(v.y); a[3] += bfhi(v.y);
    a[4] += bflo(v.z); a[5] += bfhi(v.z);
    a[6] += bflo(v.w); a[7] += bfhi(v.w);
}

__device__ __forceinline__ uint4 pack8(const float* a, float dv) {
    uint4 pk;
    pk.x = (unsigned int)f2bf(a[0] * dv) | ((unsigned int)f2bf(a[1] * dv) << 16);
    pk.y = (unsigned int)f2bf(a[2] * dv) | ((unsigned int)f2bf(a[3] * dv) << 16);
    pk.z = (unsigned int)f2bf(a[4] * dv) | ((unsigned int)f2bf(a[5] * dv) << 16);
    pk.w = (unsigned int)f2bf(a[6] * dv) | ((unsigned int)f2bf(a[7] * dv) << 16);
    return pk;
}

// ---------------------------------------------------------------------------
// prep: blocks 0..127 zero cnt; block 128 zeros hs1/hs2 sentinel rows;
// blocks 129..272 pack weights into MFMA B-fragment layout.
// Fragment f = nt*(K/32)+ks holds lane l elem j = W[ks*32+(l>>4)*8+j][nt*16+(l&15)].
// ---------------------------------------------------------------------------
__global__ __launch_bounds__(256) void prep_kernel(
    int* __restrict__ cnt, unsigned int* __restrict__ pad1,
    unsigned int* __restrict__ pad2,
    const float* __restrict__ W1, unsigned short* __restrict__ Wp1,
    const float* __restrict__ W2, unsigned short* __restrict__ Wp2) {
    int b = blockIdx.x;
    int t = threadIdx.x;
    if (b < 128) {
        cnt[b * 256 + t] = 0;
    } else if (b == 128) {
        if (t < 32) pad1[t] = 0;   // hs1 sentinel row (64 bf16)
        if (t < 64) pad2[t] = 0;   // hs2 sentinel row (128 bf16)
    } else {
        if (t >= 64) return;
        int fb = b - 129;
        const float* W; unsigned short* Wp; int K, N, f;
        if (fb < 16) { W = W1; Wp = Wp1; K = 64; N = 128; f = fb; }
        else         { W = W2; Wp = Wp2; K = 128; N = 512; f = fb - 16; }
        int l = t;  // 0..63
        int KS = K / 32;
        int nt = f / KS, ks = f % KS;
        int ncol = nt * 16 + (l & 15);
        int k0 = ks * 32 + (l >> 4) * 8;
        unsigned short v[8];
        #pragma unroll
        for (int j = 0; j < 8; j++) v[j] = f2bf(W[(size_t)(k0 + j) * N + ncol]);
        *(uint4*)&Wp[((size_t)f * 64 + l) * 8] = *(uint4*)v;
    }
}

// count degrees AND record each edge's slot within its destination's segment
__global__ void count_kernel(const int* __restrict__ dst, int* __restrict__ cnt,
                             int* __restrict__ epos, int E) {
    int e = blockIdx.x * blockDim.x + threadIdx.x;
    if (e < E) epos[e] = atomicAdd(&cnt[dst[e]], 1);
}

// --- parallel exclusive scan over padded counts ((c+7)&~7) ---
// A: per-block sums + dinv
__global__ __launch_bounds__(256) void scanA_kernel(const int* __restrict__ cnt,
                                                    int* __restrict__ blockSums,
                                                    float* __restrict__ dinv) {
    __shared__ int red[256];
    int t = threadIdx.x;
    int i = blockIdx.x * 256 + t;
    int c = cnt[i];
    dinv[i] = rsqrtf((float)(c + 1));
    red[t] = (c + 7) & ~7;
    __syncthreads();
    for (int s = 128; s > 0; s >>= 1) {
        if (t < s) red[t] += red[t + s];
        __syncthreads();
    }
    if (t == 0) blockSums[blockIdx.x] = red[0];
}

// C: block-local scan + inline scan of the 128 block sums -> indptr,
// sentinel pad-fill of ssrc
__global__ __launch_bounds__(256) void scanC_kernel(
    const int* __restrict__ cnt, const int* __restrict__ bsums,
    int* __restrict__ indptr, int* __restrict__ ssrc, int n) {
    __shared__ int sc[256];
    __shared__ int bs[128];
    int t = threadIdx.x;
    int ownSum = bsums[blockIdx.x];
    if (t < 128) bs[t] = bsums[t];
    int i = blockIdx.x * 256 + t;
    int c = cnt[i];
    int pc = (c + 7) & ~7;
    sc[t] = pc;
    __syncthreads();
    for (int off = 1; off < 128; off <<= 1) {
        int v = (t >= off && t < 128) ? bs[t - off] : 0;
        __syncthreads();
        if (t < 128) bs[t] += v;
        __syncthreads();
    }
    for (int off = 1; off < 256; off <<= 1) {
        int v = t >= off ? sc[t - off] : 0;
        __syncthreads();
        sc[t] += v;
        __syncthreads();
    }
    int blockOff = bs[blockIdx.x] - ownSum;  // exclusive block offset
    int ip = blockOff + sc[t] - pc;          // exclusive elem offset
    indptr[i] = ip;
    for (int k = c; k < pc; k++) ssrc[ip + k] = n;  // sentinel zero-row
    if (i == n - 1) indptr[n] = blockOff + sc[t];
}

// ---------------------------------------------------------------------------
// scatter (blocks 0..nb_scatter-1) || cov_enc (remaining 128 blocks).
// ---------------------------------------------------------------------------
__global__ __launch_bounds__(256) void scatter_cov_kernel(
    const int* __restrict__ src, const int* __restrict__ dst,
    const int* __restrict__ epos, const int* __restrict__ indptr,
    int* __restrict__ ssrc, int E, int nb_scatter,
    const float* __restrict__ x, const float* __restrict__ w_e1,
    const float* __restrict__ b_e1, const float* __restrict__ dinv,
    unsigned short* __restrict__ hs1) {
    int t = threadIdx.x;
    if ((int)blockIdx.x < nb_scatter) {
        int e = blockIdx.x * 256 + t;
        if (e < E) ssrc[indptr[dst[e]] + epos[e]] = src[e];
        return;
    }
    // ---- cov_enc part ----
    __shared__ float Wl[12 * 64];
    __shared__ float Bl[64];
    __shared__ float xs[280 * 3];
    int cb = blockIdx.x - nb_scatter;  // 0..127
    for (int i = t; i < 768; i += 256) Wl[i] = w_e1[i];
    if (t < 64) Bl[t] = b_e1[t];
    int p0 = cb * 256;
    int n0 = p0 & 4095;
    const float* xb = x + (size_t)(p0 - n0) * 3;  // batch base (256 | 4096)
    for (int idx = t; idx < 840; idx += 256) {
        int slot = idx / 3, d = idx - slot * 3;
        int g = n0 - 12 + slot;
        g = g < 0 ? 0 : (g > 4095 ? 4095 : g);
        xs[idx] = xb[g * 3 + d];
    }
    __syncthreads();
    int p = p0 + t;
    int n = n0 + t;
    int lo = n - 12 < 0 ? 0 : n - 12;
    int hi = n + 12 > 4095 ? 4095 : n + 12;
    int slo = lo - n0 + 12, shi = hi - n0 + 12;
    float sx = 0.f, sy = 0.f, sz = 0.f;
    float sxx = 0.f, sxy = 0.f, sxz = 0.f, syy = 0.f, syz = 0.f, szz = 0.f;
    for (int s = slo; s <= shi; s++) {
        float xv = xs[s * 3 + 0], yv = xs[s * 3 + 1], zv = xs[s * 3 + 2];
        sx += xv; sy += yv; sz += zv;
        sxx = fmaf(xv, xv, sxx); sxy = fmaf(xv, yv, sxy); sxz = fmaf(xv, zv, sxz);
        syy = fmaf(yv, yv, syy); syz = fmaf(yv, zv, syz); szz = fmaf(zv, zv, szz);
    }
    float cntf = (float)(shi - slo + 1);
    float rin = 1.f / cntf;
    float mx = sx * rin, my = sy * rin, mz = sz * rin;
    const float inv23 = 1.f / 23.f;
    float c00 = (sxx - sx * mx) * inv23;
    float c01 = (sxy - sx * my) * inv23;
    float c02 = (sxz - sx * mz) * inv23;
    float c11 = (syy - sy * my) * inv23;
    float c12 = (syz - sy * mz) * inv23;
    float c22 = (szz - sz * mz) * inv23;
    float feat[12];
    feat[0] = xs[(t + 12) * 3 + 0];
    feat[1] = xs[(t + 12) * 3 + 1];
    feat[2] = xs[(t + 12) * 3 + 2];
    feat[3] = c00; feat[4] = c01; feat[5]  = c02;
    feat[6] = c01; feat[7] = c11; feat[8]  = c12;
    feat[9] = c02; feat[10] = c12; feat[11] = c22;
    float dv = dinv[p];
    unsigned int* hp = (unsigned int*)(hs1 + (size_t)p * 64);
    for (int c = 0; c < 64; c += 2) {
        float a0 = Bl[c], a1 = Bl[c + 1];
        #pragma unroll
        for (int i = 0; i < 12; i++) {
            a0 = fmaf(feat[i], Wl[i * 64 + c], a0);
            a1 = fmaf(feat[i], Wl[i * 64 + c + 1], a1);
        }
        unsigned int pk = (unsigned int)f2bf(dv * selu_f(a0)) |
                          ((unsigned int)f2bf(dv * selu_f(a1)) << 16);
        hp[c >> 1] = pk;
    }
}

// ---------------------------------------------------------------------------
// Fused GCN1: per block, aggregate 128 nodes (C=64) straight into the MFMA
// LDS A-buffer, then gemm vs Wp1 (K=64, N=128) and write bf16 hs2
// (dinv-prescaled).  GEMM is small (64 acc VGPRs) so occupancy stays OK.
// ---------------------------------------------------------------------------
__global__ __launch_bounds__(256) void gcn1_kernel(
    const unsigned short* __restrict__ hs1, const float* __restrict__ dinv,
    const int* __restrict__ indptr, const int* __restrict__ ssrc,
    const unsigned short* __restrict__ Wp, const float* __restrict__ bias,
    unsigned short* __restrict__ hs2) {
    constexpr int LDA = 72;  // 64 + 8 bf16 pad
    __shared__ unsigned short As[128 * LDA];
    int t = threadIdx.x;
    int R0 = blockIdx.x * 128;
    const uint4* hp = (const uint4*)hs1;

    // aggregation phase: 128 nodes x 8 uint4-chunks = 1024 tasks
    for (int idx = t; idx < 1024; idx += 256) {
        int nl = idx >> 3, cq = idx & 7;
        int node = R0 + nl;
        float a[8];
        {
            uint4 u = hp[(size_t)node * 8 + cq];
            a[0] = bflo(u.x); a[1] = bfhi(u.x);
            a[2] = bflo(u.y); a[3] = bfhi(u.y);
            a[4] = bflo(u.z); a[5] = bfhi(u.z);
            a[6] = bflo(u.w); a[7] = bfhi(u.w);
        }
        int beg = indptr[node], end = indptr[node + 1];
        for (int j = beg; j < end; j += 8) {
            int s[8];
            #pragma unroll
            for (int q = 0; q < 8; q++) s[q] = ssrc[j + q];
            uint4 v[8];
            #pragma unroll
            for (int q = 0; q < 8; q++) v[q] = hp[(size_t)s[q] * 8 + cq];
            #pragma unroll
            for (int q = 0; q < 8; q++) acc8(a, v[q]);
        }
        *(uint4*)&As[nl * LDA + cq * 8] = pack8(a, dinv[node]);
    }
    __syncthreads();

    // gemm phase: K=64 (KS=2), N=128, epilogue dinv*selu -> bf16 hs2
    int wave = t >> 6, l = t & 63;
    int ml = l & 15, q = l >> 4;
    int wr = wave * 32;
    f32x4 acc[2][8];
    #pragma unroll
    for (int mf = 0; mf < 2; mf++)
        #pragma unroll
        for (int nf = 0; nf < 8; nf++) acc[mf][nf] = (f32x4){0.f, 0.f, 0.f, 0.f};
    const bf16x8* wp8 = (const bf16x8*)Wp;
    #pragma unroll
    for (int ks = 0; ks < 2; ks++) {
        bf16x8 af[2];
        #pragma unroll
        for (int mf = 0; mf < 2; mf++)
            af[mf] = *(const bf16x8*)&As[(wr + mf * 16 + ml) * LDA + ks * 32 + q * 8];
        bf16x8 bfr[8];
        #pragma unroll
        for (int nf = 0; nf < 8; nf++)
            bfr[nf] = wp8[(size_t)(nf * 2 + ks) * 64 + l];
        #pragma unroll
        for (int mf = 0; mf < 2; mf++)
            #pragma unroll
            for (int nf = 0; nf < 8; nf++)
                acc[mf][nf] = __builtin_amdgcn_mfma_f32_16x16x32_bf16(
                    af[mf], bfr[nf], acc[mf][nf], 0, 0, 0);
    }
    float bj[8];
    #pragma unroll
    for (int nf = 0; nf < 8; nf++) bj[nf] = bias[nf * 16 + ml];
    #pragma unroll
    for (int mf = 0; mf < 2; mf++) {
        #pragma unroll
        for (int r = 0; r < 4; r++) {
            int row = R0 + wr + mf * 16 + q * 4 + r;
            float dv = dinv[row];
            #pragma unroll
            for (int nf = 0; nf < 8; nf++) {
                float v = dv * selu_f(acc[mf][nf][r] + bj[nf]);
                hs2[(size_t)row * 128 + nf * 16 + ml] = f2bf(v);
            }
        }
    }
}

// ---------------------------------------------------------------------------
// Aggregation (C=128), STANDALONE for max occupancy (latency-bound gather):
// out[d] = dinv[d]*(hs[d] + sum hs[s]), 8ch/thread, 8-deep gather batching.
// ---------------------------------------------------------------------------
__global__ __launch_bounds__(256) void agg128_kernel(
    const unsigned short* __restrict__ hs, const float* __restrict__ dinv,
    const int* __restrict__ indptr, const int* __restrict__ ssrc,
    unsigned short* __restrict__ out, int n_nodes) {
    constexpr int TPN = 16;
    int node = blockIdx.x * (256 / TPN) + threadIdx.x / TPN;
    int cq = threadIdx.x % TPN;
    if (node >= n_nodes) return;
    const uint4* hp = (const uint4*)hs;
    float a[8];
    {
        uint4 u = hp[(size_t)node * TPN + cq];
        a[0] = bflo(u.x); a[1] = bfhi(u.x);
        a[2] = bflo(u.y); a[3] = bfhi(u.y);
        a[4] = bflo(u.z); a[5] = bfhi(u.z);
        a[6] = bflo(u.w); a[7] = bfhi(u.w);
    }
    int beg = indptr[node], end = indptr[node + 1];
    for (int j = beg; j < end; j += 8) {
        int s[8];
        #pragma unroll
        for (int q = 0; q < 8; q++) s[q] = ssrc[j + q];
        uint4 v[8];
        #pragma unroll
        for (int q = 0; q < 8; q++) v[q] = hp[(size_t)s[q] * TPN + cq];
        #pragma unroll
        for (int q = 0; q < 8; q++) acc8(a, v[q]);
    }
    ((uint4*)out)[(size_t)node * TPN + cq] = pack8(a, dinv[node]);
}

// ---------------------------------------------------------------------------
// MFMA bf16 GEMM (K=128): selu + per-tile column max -> pmax
// ---------------------------------------------------------------------------
__global__ __launch_bounds__(256) void gemm2_kernel(
    const unsigned short* __restrict__ A, const unsigned short* __restrict__ Wp,
    const float* __restrict__ bias, float* __restrict__ pmax, int Nfull) {
    constexpr int KS = 4;
    constexpr int LDA = 136;  // 128 + 8
    constexpr int CPR = 16;
    __shared__ unsigned short As[128 * LDA];
    int t = threadIdx.x;
    int wave = t >> 6, l = t & 63;
    int ml = l & 15, q = l >> 4;
    int R0 = blockIdx.x * 128;
    int cb = blockIdx.y * 128;

    for (int c = t; c < 128 * CPR; c += 256) {
        int row = c / CPR, off = c % CPR;
        *(uint4*)&As[row * LDA + off * 8] =
            *(const uint4*)&A[(size_t)(R0 + row) * 128 + off * 8];
    }
    __syncthreads();

    f32x4 acc[2][8];
    #pragma unroll
    for (int mf = 0; mf < 2; mf++)
        #pragma unroll
        for (int nf = 0; nf < 8; nf++) acc[mf][nf] = (f32x4){0.f, 0.f, 0.f, 0.f};

    const bf16x8* wp8 = (const bf16x8*)Wp;
    int wr = wave * 32;
    #pragma unroll
    for (int ks = 0; ks < KS; ks++) {
        bf16x8 af[2];
        #pragma unroll
        for (int mf = 0; mf < 2; mf++)
            af[mf] = *(const bf16x8*)&As[(wr + mf * 16 + ml) * LDA + ks * 32 + q * 8];
        bf16x8 bfr[8];
        #pragma unroll
        for (int nf = 0; nf < 8; nf++)
            bfr[nf] = wp8[(size_t)(((cb >> 4) + nf) * KS + ks) * 64 + l];
        #pragma unroll
        for (int mf = 0; mf < 2; mf++)
            #pragma unroll
            for (int nf = 0; nf < 8; nf++)
                acc[mf][nf] = __builtin_amdgcn_mfma_f32_16x16x32_bf16(
                    af[mf], bfr[nf], acc[mf][nf], 0, 0, 0);
    }

    // selu + column max; C/D layout: col = ml, row = q*4 + r
    float cmax[8];
    #pragma unroll
    for (int nf = 0; nf < 8; nf++) {
        float bj = bias[cb + nf * 16 + ml];
        float v = -INFINITY;
        #pragma unroll
        for (int mf = 0; mf < 2; mf++)
            #pragma unroll
            for (int r = 0; r < 4; r++)
                v = fmaxf(v, selu_f(acc[mf][nf][r] + bj));
        v = fmaxf(v, __shfl_xor(v, 16, 64));
        v = fmaxf(v, __shfl_xor(v, 32, 64));
        cmax[nf] = v;
    }
    __syncthreads();  // before reusing As as f32 scratch
    float* redf = (float*)As;  // [4 waves][128 cols]
    if (ml == l) {  // lanes 0..15
        #pragma unroll
        for (int nf = 0; nf < 8; nf++) redf[wave * 128 + nf * 16 + l] = cmax[nf];
    }
    __syncthreads();
    if (t < 128) {
        float v = redf[t];
        v = fmaxf(v, redf[128 + t]);
        v = fmaxf(v, redf[256 + t]);
        v = fmaxf(v, redf[384 + t]);
        pmax[(size_t)blockIdx.x * Nfull + cb + t] = v;
    }
}

// ---------------------------------------------------------------------------
// lat + decode fused (one block per batch):
// m[b][c] = max over 32 pmax tiles; lat = selu(m@w_e2+b_e2);
// latw1/latw2 = lat @ w_d1[:512]/w_d2[:512] + bias; then decode the batch's
// 4096 points in-kernel (grid fold, two 3-wide folds).
// ---------------------------------------------------------------------------
__global__ __launch_bounds__(256) void lat_decode_kernel(
    const float* __restrict__ pmax, const float* __restrict__ w_e2,
    const float* __restrict__ b_e2, const float* __restrict__ w_d1,
    const float* __restrict__ b_d1, const float* __restrict__ w_d2,
    const float* __restrict__ b_d2, float* __restrict__ out) {
    int b = blockIdx.x;
    int t = threadIdx.x;
    __shared__ float ml[512], ll[512];
    __shared__ float red[6][256];
    __shared__ float lw[6];
    for (int c = t; c < 512; c += 256) {
        const float* p = pmax + (size_t)(b * 32) * 512 + c;
        float v = -INFINITY;
        #pragma unroll
        for (int k = 0; k < 32; k++) v = fmaxf(v, p[k * 512]);
        ml[c] = v;
    }
    __syncthreads();
    for (int cc = 0; cc < 2; cc++) {
        int c = t + cc * 256;
        float acc = b_e2[c];
        for (int k = 0; k < 512; k++) acc = fmaf(ml[k], w_e2[k * 512 + c], acc);
        ll[c] = selu_f(acc);
    }
    __syncthreads();
    float p[6] = {0.f, 0.f, 0.f, 0.f, 0.f, 0.f};
    for (int k = t; k < 512; k += 256) {
        float lv = ll[k];
        #pragma unroll
        for (int j = 0; j < 3; j++) {
            p[j]     = fmaf(lv, w_d1[k * 3 + j], p[j]);
            p[3 + j] = fmaf(lv, w_d2[k * 3 + j], p[3 + j]);
        }
    }
    #pragma unroll
    for (int j = 0; j < 6; j++) red[j][t] = p[j];
    __syncthreads();
    for (int s = 128; s > 0; s >>= 1) {
        if (t < s) {
            #pragma unroll
            for (int j = 0; j < 6; j++) red[j][t] += red[j][t + s];
        }
        __syncthreads();
    }
    if (t < 3) {
        lw[t]     = red[t][0] + b_d1[t];
        lw[3 + t] = red[3 + t][0] + b_d2[t];
    }
    __syncthreads();
    // ---- decode this batch's 4096 points ----
    float l10 = lw[0], l11 = lw[1], l12 = lw[2];
    float l20 = lw[3], l21 = lw[4], l22 = lw[5];
    float w1a0 = w_d1[1536 + 0], w1a1 = w_d1[1536 + 1], w1a2 = w_d1[1536 + 2];
    float w1b0 = w_d1[1539 + 0], w1b1 = w_d1[1539 + 1], w1b2 = w_d1[1539 + 2];
    float w2a0 = w_d2[1536 + 0], w2a1 = w_d2[1536 + 1], w2a2 = w_d2[1536 + 2];
    float w2b0 = w_d2[1539 + 0], w2b1 = w_d2[1539 + 1], w2b2 = w_d2[1539 + 2];
    float w2c0 = w_d2[1542 + 0], w2c1 = w_d2[1542 + 1], w2c2 = w_d2[1542 + 2];
    for (int n = t; n < 4096; n += 256) {
        int i = n / 46;
        int j = n - i * 46;
        float y0 = fmaf((float)i, 119.f / 90.f, 1.f);
        float y1 = fmaf((float)j, 59.f / 45.f, 1.f);
        float k0 = selu_f(l10 + y0 * w1a0 + y1 * w1b0);
        float k1 = selu_f(l11 + y0 * w1a1 + y1 * w1b1);
        float k2 = selu_f(l12 + y0 * w1a2 + y1 * w1b2);
        float o0 = selu_f(l20 + k0 * w2a0 + k1 * w2b0 + k2 * w2c0);
        float o1 = selu_f(l21 + k0 * w2a1 + k1 * w2b1 + k2 * w2c1);
        float o2 = selu_f(l22 + k0 * w2a2 + k1 * w2b2 + k2 * w2c2);
        size_t pidx = (size_t)(b * 4096 + n) * 3;
        out[pidx + 0] = o0;
        out[pidx + 1] = o1;
        out[pidx + 2] = o2;
    }
}

// ---------------------------------------------------------------------------
extern "C" void kernel_launch(void* const* d_in, const int* in_sizes, int n_in,
                              void* d_out, int out_size, void* d_ws, size_t ws_size,
                              hipStream_t stream) {
    const float* x    = (const float*)d_in[0];
    const int*   knn  = (const int*)d_in[1];
    const float* w_e1 = (const float*)d_in[2];
    const float* b_e1 = (const float*)d_in[3];
    const float* w_g1 = (const float*)d_in[4];
    const float* b_g1 = (const float*)d_in[5];
    const float* w_g2 = (const float*)d_in[6];
    const float* b_g2 = (const float*)d_in[7];
    const float* w_e2 = (const float*)d_in[8];
    const float* b_e2 = (const float*)d_in[9];
    const float* w_d1 = (const float*)d_in[10];
    const float* b_d1 = (const float*)d_in[11];
    const float* w_d2 = (const float*)d_in[12];
    const float* b_d2 = (const float*)d_in[13];
    float* out = (float*)d_out;

    const int BN = in_sizes[0] / 3;   // 32768
    const int E  = in_sizes[1] / 2;   // 524288
    const int Bb = BN / 4096;         // 8
    const int* src = knn;
    const int* dst = knn + E;

    size_t off = 0;
    auto alloc = [&](size_t bytes) -> void* {
        void* p = (char*)d_ws + off;
        off += (bytes + 255) & ~(size_t)255;
        return p;
    };
    unsigned short* hs1 = (unsigned short*)alloc((size_t)(BN + 1) * 64 * 2);
    unsigned short* hs2 = (unsigned short*)alloc((size_t)(BN + 1) * 128 * 2);
    unsigned short* a2  = (unsigned short*)alloc((size_t)BN * 128 * 2);
    unsigned short* Wp1 = (unsigned short*)alloc((size_t)16 * 64 * 8 * 2);
    unsigned short* Wp2 = (unsigned short*)alloc((size_t)128 * 64 * 8 * 2);
    float* pmax   = (float*)alloc((size_t)(BN / 128) * 512 * 4);
    float* dinv   = (float*)alloc((size_t)BN * 4);
    int*   cnt    = (int*)alloc((size_t)BN * 4);
    int*   epos   = (int*)alloc((size_t)E * 4);
    int*   indptr = (int*)alloc((size_t)(BN + 1) * 4);
    int*   bsums  = (int*)alloc((size_t)128 * 4);
    int*   ssrc   = (int*)alloc((size_t)(E + 7 * BN + 1024) * 4);
    (void)ws_size;

    const int nb_scatter = (E + 255) / 256;  // 2048

    // prep: zero cnt + sentinel rows, pack both weight matrices
    prep_kernel<<<273, 256, 0, stream>>>(
        cnt, (unsigned int*)(hs1 + (size_t)BN * 64),
        (unsigned int*)(hs2 + (size_t)BN * 128), w_g1, Wp1, w_g2, Wp2);
    // count + per-edge slot
    count_kernel<<<(E + 255) / 256, 256, 0, stream>>>(dst, cnt, epos, E);
    scanA_kernel<<<BN / 256, 256, 0, stream>>>(cnt, bsums, dinv);
    scanC_kernel<<<BN / 256, 256, 0, stream>>>(cnt, bsums, indptr, ssrc, BN);
    // scatter || encoder (independent after scanA/scanC)
    scatter_cov_kernel<<<nb_scatter + 128, 256, 0, stream>>>(
        src, dst, epos, indptr, ssrc, E, nb_scatter,
        x, w_e1, b_e1, dinv, hs1);

    // GCN1 fused: agg(64) -> MFMA K=64 -> bf16 hs2 (dinv-prescaled)
    gcn1_kernel<<<BN / 128, 256, 0, stream>>>(hs1, dinv, indptr, ssrc, Wp1, b_g1, hs2);

    // GCN2 split (gather needs full occupancy): agg(128) -> MFMA + column max
    agg128_kernel<<<BN / 16, 256, 0, stream>>>(hs2, dinv, indptr, ssrc, a2, BN);
    gemm2_kernel<<<dim3(BN / 128, 4), 256, 0, stream>>>(a2, Wp2, b_g2, pmax, 512);

    // max-pool + latent + decoder (fused, one block per batch)
    lat_decode_kernel<<<Bb, 256, 0, stream>>>(pmax, w_e2, b_e2, w_d1, b_d1,
                                              w_d2, b_d2, out);
}

// Round 9
// 214.186 us; speedup vs baseline: 1.1699x; 1.1114x over previous
//
#include <hip/hip_runtime.h>
#include <math.h>

#define SELU_SCALE 1.0507009873554804934193349852946f
#define SELU_ALPHA 1.6732632423543772848170429916717f

typedef short bf16x8 __attribute__((ext_vector_type(8)));
typedef float f32x4 __attribute__((ext_vector_type(4)));

__device__ __forceinline__ float selu_f(float x) {
    return SELU_SCALE * (x > 0.f ? x : SELU_ALPHA * expm1f(x));
}

__device__ __forceinline__ unsigned short f2bf(float f) {
    unsigned int u = __float_as_uint(f);
    u += 0x7FFF + ((u >> 16) & 1);  // round-to-nearest-even
    return (unsigned short)(u >> 16);
}
__device__ __forceinline__ float bflo(unsigned int u) { return __uint_as_float(u << 16); }
__device__ __forceinline__ float bfhi(unsigned int u) { return __uint_as_float(u & 0xFFFF0000u); }

// monotonic float<->uint encoding (order-preserving); max in uint == max in float
__device__ __forceinline__ unsigned int fenc(float f) {
    unsigned int u = __float_as_uint(f);
    return (u & 0x80000000u) ? ~u : (u | 0x80000000u);
}
__device__ __forceinline__ float fdec(unsigned int u) {
    return __uint_as_float((u & 0x80000000u) ? (u ^ 0x80000000u) : ~u);
}

__device__ __forceinline__ void acc8(float* a, uint4 v) {
    a[0] += bflo(v.x); a[1] += bfhi(v.x);
    a[2] += bflo(v.y); a[3] += bfhi(v.y);
    a[4] += bflo(v.z); a[5] += bfhi(v.z);
    a[6] += bflo(v.w); a[7] += bfhi(v.w);
}

__device__ __forceinline__ uint4 pack8(const float* a, float dv) {
    uint4 pk;
    pk.x = (unsigned int)f2bf(a[0] * dv) | ((unsigned int)f2bf(a[1] * dv) << 16);
    pk.y = (unsigned int)f2bf(a[2] * dv) | ((unsigned int)f2bf(a[3] * dv) << 16);
    pk.z = (unsigned int)f2bf(a[4] * dv) | ((unsigned int)f2bf(a[5] * dv) << 16);
    pk.w = (unsigned int)f2bf(a[6] * dv) | ((unsigned int)f2bf(a[7] * dv) << 16);
    return pk;
}

// ---------------------------------------------------------------------------
// prep: blocks 0..127 zero cnt; block 128 zeros sentinel rows + m_enc;
// blocks 129..272 pack weights into MFMA B-fragment layout.
// ---------------------------------------------------------------------------
__global__ __launch_bounds__(256) void prep_kernel(
    int* __restrict__ cnt, unsigned int* __restrict__ pad1,
    unsigned int* __restrict__ pad2, unsigned int* __restrict__ menc,
    const float* __restrict__ W1, unsigned short* __restrict__ Wp1,
    const float* __restrict__ W2, unsigned short* __restrict__ Wp2) {
    int b = blockIdx.x;
    int t = threadIdx.x;
    if (b < 128) {
        cnt[b * 256 + t] = 0;
    } else if (b == 128) {
        if (t < 32) pad1[t] = 0;   // hs1 sentinel row (64 bf16)
        if (t < 64) pad2[t] = 0;   // hs2 sentinel row (128 bf16)
        for (int i = t; i < 4096; i += 256) menc[i] = 0u;  // enc(-NaN) < all reals
    } else {
        if (t >= 64) return;
        int fb = b - 129;
        const float* W; unsigned short* Wp; int K, N, f;
        if (fb < 16) { W = W1; Wp = Wp1; K = 64; N = 128; f = fb; }
        else         { W = W2; Wp = Wp2; K = 128; N = 512; f = fb - 16; }
        int l = t;  // 0..63
        int KS = K / 32;
        int nt = f / KS, ks = f % KS;
        int ncol = nt * 16 + (l & 15);
        int k0 = ks * 32 + (l >> 4) * 8;
        unsigned short v[8];
        #pragma unroll
        for (int j = 0; j < 8; j++) v[j] = f2bf(W[(size_t)(k0 + j) * N + ncol]);
        *(uint4*)&Wp[((size_t)f * 64 + l) * 8] = *(uint4*)v;
    }
}

// count degrees AND record each edge's slot within its destination's segment
__global__ void count_kernel(const int* __restrict__ dst, int* __restrict__ cnt,
                             int* __restrict__ epos, int E) {
    int e = blockIdx.x * blockDim.x + threadIdx.x;
    if (e < E) epos[e] = atomicAdd(&cnt[dst[e]], 1);
}

// --- parallel exclusive scan over padded counts ((c+7)&~7) ---
__global__ __launch_bounds__(256) void scanA_kernel(const int* __restrict__ cnt,
                                                    int* __restrict__ blockSums,
                                                    float* __restrict__ dinv) {
    __shared__ int red[256];
    int t = threadIdx.x;
    int i = blockIdx.x * 256 + t;
    int c = cnt[i];
    dinv[i] = rsqrtf((float)(c + 1));
    red[t] = (c + 7) & ~7;
    __syncthreads();
    for (int s = 128; s > 0; s >>= 1) {
        if (t < s) red[t] += red[t + s];
        __syncthreads();
    }
    if (t == 0) blockSums[blockIdx.x] = red[0];
}

__global__ __launch_bounds__(256) void scanC_kernel(
    const int* __restrict__ cnt, const int* __restrict__ bsums,
    int* __restrict__ indptr, int* __restrict__ ssrc, int n) {
    __shared__ int sc[256];
    __shared__ int bs[128];
    int t = threadIdx.x;
    int ownSum = bsums[blockIdx.x];
    if (t < 128) bs[t] = bsums[t];
    int i = blockIdx.x * 256 + t;
    int c = cnt[i];
    int pc = (c + 7) & ~7;
    sc[t] = pc;
    __syncthreads();
    for (int off = 1; off < 128; off <<= 1) {
        int v = (t >= off && t < 128) ? bs[t - off] : 0;
        __syncthreads();
        if (t < 128) bs[t] += v;
        __syncthreads();
    }
    for (int off = 1; off < 256; off <<= 1) {
        int v = t >= off ? sc[t - off] : 0;
        __syncthreads();
        sc[t] += v;
        __syncthreads();
    }
    int blockOff = bs[blockIdx.x] - ownSum;  // exclusive block offset
    int ip = blockOff + sc[t] - pc;          // exclusive elem offset
    indptr[i] = ip;
    for (int k = c; k < pc; k++) ssrc[ip + k] = n;  // sentinel zero-row
    if (i == n - 1) indptr[n] = blockOff + sc[t];
}

// ---------------------------------------------------------------------------
// scatter (blocks 0..nb_scatter-1) || cov_enc (remaining 128 blocks).
// ---------------------------------------------------------------------------
__global__ __launch_bounds__(256) void scatter_cov_kernel(
    const int* __restrict__ src, const int* __restrict__ dst,
    const int* __restrict__ epos, const int* __restrict__ indptr,
    int* __restrict__ ssrc, int E, int nb_scatter,
    const float* __restrict__ x, const float* __restrict__ w_e1,
    const float* __restrict__ b_e1, const float* __restrict__ dinv,
    unsigned short* __restrict__ hs1) {
    int t = threadIdx.x;
    if ((int)blockIdx.x < nb_scatter) {
        int e = blockIdx.x * 256 + t;
        if (e < E) ssrc[indptr[dst[e]] + epos[e]] = src[e];
        return;
    }
    // ---- cov_enc part ----
    __shared__ float Wl[12 * 64];
    __shared__ float Bl[64];
    __shared__ float xs[280 * 3];
    int cb = blockIdx.x - nb_scatter;  // 0..127
    for (int i = t; i < 768; i += 256) Wl[i] = w_e1[i];
    if (t < 64) Bl[t] = b_e1[t];
    int p0 = cb * 256;
    int n0 = p0 & 4095;
    const float* xb = x + (size_t)(p0 - n0) * 3;  // batch base (256 | 4096)
    for (int idx = t; idx < 840; idx += 256) {
        int slot = idx / 3, d = idx - slot * 3;
        int g = n0 - 12 + slot;
        g = g < 0 ? 0 : (g > 4095 ? 4095 : g);
        xs[idx] = xb[g * 3 + d];
    }
    __syncthreads();
    int p = p0 + t;
    int n = n0 + t;
    int lo = n - 12 < 0 ? 0 : n - 12;
    int hi = n + 12 > 4095 ? 4095 : n + 12;
    int slo = lo - n0 + 12, shi = hi - n0 + 12;
    float sx = 0.f, sy = 0.f, sz = 0.f;
    float sxx = 0.f, sxy = 0.f, sxz = 0.f, syy = 0.f, syz = 0.f, szz = 0.f;
    for (int s = slo; s <= shi; s++) {
        float xv = xs[s * 3 + 0], yv = xs[s * 3 + 1], zv = xs[s * 3 + 2];
        sx += xv; sy += yv; sz += zv;
        sxx = fmaf(xv, xv, sxx); sxy = fmaf(xv, yv, sxy); sxz = fmaf(xv, zv, sxz);
        syy = fmaf(yv, yv, syy); syz = fmaf(yv, zv, syz); szz = fmaf(zv, zv, szz);
    }
    float cntf = (float)(shi - slo + 1);
    float rin = 1.f / cntf;
    float mx = sx * rin, my = sy * rin, mz = sz * rin;
    const float inv23 = 1.f / 23.f;
    float c00 = (sxx - sx * mx) * inv23;
    float c01 = (sxy - sx * my) * inv23;
    float c02 = (sxz - sx * mz) * inv23;
    float c11 = (syy - sy * my) * inv23;
    float c12 = (syz - sy * mz) * inv23;
    float c22 = (szz - sz * mz) * inv23;
    float feat[12];
    feat[0] = xs[(t + 12) * 3 + 0];
    feat[1] = xs[(t + 12) * 3 + 1];
    feat[2] = xs[(t + 12) * 3 + 2];
    feat[3] = c00; feat[4] = c01; feat[5]  = c02;
    feat[6] = c01; feat[7] = c11; feat[8]  = c12;
    feat[9] = c02; feat[10] = c12; feat[11] = c22;
    float dv = dinv[p];
    unsigned int* hp = (unsigned int*)(hs1 + (size_t)p * 64);
    for (int c = 0; c < 64; c += 2) {
        float a0 = Bl[c], a1 = Bl[c + 1];
        #pragma unroll
        for (int i = 0; i < 12; i++) {
            a0 = fmaf(feat[i], Wl[i * 64 + c], a0);
            a1 = fmaf(feat[i], Wl[i * 64 + c + 1], a1);
        }
        unsigned int pk = (unsigned int)f2bf(dv * selu_f(a0)) |
                          ((unsigned int)f2bf(dv * selu_f(a1)) << 16);
        hp[c >> 1] = pk;
    }
}

// ---------------------------------------------------------------------------
// Fused GCN1: aggregate 128 nodes (C=64) into LDS, MFMA K=64 N=128,
// write bf16 hs2 (dinv-prescaled).
// ---------------------------------------------------------------------------
__global__ __launch_bounds__(256) void gcn1_kernel(
    const unsigned short* __restrict__ hs1, const float* __restrict__ dinv,
    const int* __restrict__ indptr, const int* __restrict__ ssrc,
    const unsigned short* __restrict__ Wp, const float* __restrict__ bias,
    unsigned short* __restrict__ hs2) {
    constexpr int LDA = 72;  // 64 + 8 bf16 pad
    __shared__ unsigned short As[128 * LDA];
    int t = threadIdx.x;
    int R0 = blockIdx.x * 128;
    const uint4* hp = (const uint4*)hs1;

    for (int idx = t; idx < 1024; idx += 256) {
        int nl = idx >> 3, cq = idx & 7;
        int node = R0 + nl;
        float a[8];
        {
            uint4 u = hp[(size_t)node * 8 + cq];
            a[0] = bflo(u.x); a[1] = bfhi(u.x);
            a[2] = bflo(u.y); a[3] = bfhi(u.y);
            a[4] = bflo(u.z); a[5] = bfhi(u.z);
            a[6] = bflo(u.w); a[7] = bfhi(u.w);
        }
        int beg = indptr[node], end = indptr[node + 1];
        for (int j = beg; j < end; j += 8) {
            int s[8];
            #pragma unroll
            for (int q = 0; q < 8; q++) s[q] = ssrc[j + q];
            uint4 v[8];
            #pragma unroll
            for (int q = 0; q < 8; q++) v[q] = hp[(size_t)s[q] * 8 + cq];
            #pragma unroll
            for (int q = 0; q < 8; q++) acc8(a, v[q]);
        }
        *(uint4*)&As[nl * LDA + cq * 8] = pack8(a, dinv[node]);
    }
    __syncthreads();

    int wave = t >> 6, l = t & 63;
    int ml = l & 15, q = l >> 4;
    int wr = wave * 32;
    f32x4 acc[2][8];
    #pragma unroll
    for (int mf = 0; mf < 2; mf++)
        #pragma unroll
        for (int nf = 0; nf < 8; nf++) acc[mf][nf] = (f32x4){0.f, 0.f, 0.f, 0.f};
    const bf16x8* wp8 = (const bf16x8*)Wp;
    #pragma unroll
    for (int ks = 0; ks < 2; ks++) {
        bf16x8 af[2];
        #pragma unroll
        for (int mf = 0; mf < 2; mf++)
            af[mf] = *(const bf16x8*)&As[(wr + mf * 16 + ml) * LDA + ks * 32 + q * 8];
        bf16x8 bfr[8];
        #pragma unroll
        for (int nf = 0; nf < 8; nf++)
            bfr[nf] = wp8[(size_t)(nf * 2 + ks) * 64 + l];
        #pragma unroll
        for (int mf = 0; mf < 2; mf++)
            #pragma unroll
            for (int nf = 0; nf < 8; nf++)
                acc[mf][nf] = __builtin_amdgcn_mfma_f32_16x16x32_bf16(
                    af[mf], bfr[nf], acc[mf][nf], 0, 0, 0);
    }
    float bj[8];
    #pragma unroll
    for (int nf = 0; nf < 8; nf++) bj[nf] = bias[nf * 16 + ml];
    #pragma unroll
    for (int mf = 0; mf < 2; mf++) {
        #pragma unroll
        for (int r = 0; r < 4; r++) {
            int row = R0 + wr + mf * 16 + q * 4 + r;
            float dv = dinv[row];
            #pragma unroll
            for (int nf = 0; nf < 8; nf++) {
                float v = dv * selu_f(acc[mf][nf][r] + bj[nf]);
                hs2[(size_t)row * 128 + nf * 16 + ml] = f2bf(v);
            }
        }
    }
}

// ---------------------------------------------------------------------------
// Aggregation (C=128), standalone for max occupancy (latency-bound gather).
// ---------------------------------------------------------------------------
__global__ __launch_bounds__(256) void agg128_kernel(
    const unsigned short* __restrict__ hs, const float* __restrict__ dinv,
    const int* __restrict__ indptr, const int* __restrict__ ssrc,
    unsigned short* __restrict__ out, int n_nodes) {
    constexpr int TPN = 16;
    int node = blockIdx.x * (256 / TPN) + threadIdx.x / TPN;
    int cq = threadIdx.x % TPN;
    if (node >= n_nodes) return;
    const uint4* hp = (const uint4*)hs;
    float a[8];
    {
        uint4 u = hp[(size_t)node * TPN + cq];
        a[0] = bflo(u.x); a[1] = bfhi(u.x);
        a[2] = bflo(u.y); a[3] = bfhi(u.y);
        a[4] = bflo(u.z); a[5] = bfhi(u.z);
        a[6] = bflo(u.w); a[7] = bfhi(u.w);
    }
    int beg = indptr[node], end = indptr[node + 1];
    for (int j = beg; j < end; j += 8) {
        int s[8];
        #pragma unroll
        for (int q = 0; q < 8; q++) s[q] = ssrc[j + q];
        uint4 v[8];
        #pragma unroll
        for (int q = 0; q < 8; q++) v[q] = hp[(size_t)s[q] * TPN + cq];
        #pragma unroll
        for (int q = 0; q < 8; q++) acc8(a, v[q]);
    }
    ((uint4*)out)[(size_t)node * TPN + cq] = pack8(a, dinv[node]);
}

// ---------------------------------------------------------------------------
// MFMA bf16 GEMM (K=128): selu + column max -> atomicMax into m_enc (exact).
// ---------------------------------------------------------------------------
__global__ __launch_bounds__(256) void gemm2_kernel(
    const unsigned short* __restrict__ A, const unsigned short* __restrict__ Wp,
    const float* __restrict__ bias, unsigned int* __restrict__ menc, int Nfull) {
    constexpr int KS = 4;
    constexpr int LDA = 136;  // 128 + 8
    constexpr int CPR = 16;
    __shared__ unsigned short As[128 * LDA];
    int t = threadIdx.x;
    int wave = t >> 6, l = t & 63;
    int ml = l & 15, q = l >> 4;
    int R0 = blockIdx.x * 128;
    int cb = blockIdx.y * 128;

    for (int c = t; c < 128 * CPR; c += 256) {
        int row = c / CPR, off = c % CPR;
        *(uint4*)&As[row * LDA + off * 8] =
            *(const uint4*)&A[(size_t)(R0 + row) * 128 + off * 8];
    }
    __syncthreads();

    f32x4 acc[2][8];
    #pragma unroll
    for (int mf = 0; mf < 2; mf++)
        #pragma unroll
        for (int nf = 0; nf < 8; nf++) acc[mf][nf] = (f32x4){0.f, 0.f, 0.f, 0.f};

    const bf16x8* wp8 = (const bf16x8*)Wp;
    int wr = wave * 32;
    #pragma unroll
    for (int ks = 0; ks < KS; ks++) {
        bf16x8 af[2];
        #pragma unroll
        for (int mf = 0; mf < 2; mf++)
            af[mf] = *(const bf16x8*)&As[(wr + mf * 16 + ml) * LDA + ks * 32 + q * 8];
        bf16x8 bfr[8];
        #pragma unroll
        for (int nf = 0; nf < 8; nf++)
            bfr[nf] = wp8[(size_t)(((cb >> 4) + nf) * KS + ks) * 64 + l];
        #pragma unroll
        for (int mf = 0; mf < 2; mf++)
            #pragma unroll
            for (int nf = 0; nf < 8; nf++)
                acc[mf][nf] = __builtin_amdgcn_mfma_f32_16x16x32_bf16(
                    af[mf], bfr[nf], acc[mf][nf], 0, 0, 0);
    }

    // selu + column max; C/D layout: col = ml, row = q*4 + r
    float cmax[8];
    #pragma unroll
    for (int nf = 0; nf < 8; nf++) {
        float bj = bias[cb + nf * 16 + ml];
        float v = -INFINITY;
        #pragma unroll
        for (int mf = 0; mf < 2; mf++)
            #pragma unroll
            for (int r = 0; r < 4; r++)
                v = fmaxf(v, selu_f(acc[mf][nf][r] + bj));
        v = fmaxf(v, __shfl_xor(v, 16, 64));
        v = fmaxf(v, __shfl_xor(v, 32, 64));
        cmax[nf] = v;
    }
    __syncthreads();  // before reusing As as f32 scratch
    float* redf = (float*)As;  // [4 waves][128 cols]
    if (ml == l) {  // lanes 0..15
        #pragma unroll
        for (int nf = 0; nf < 8; nf++) redf[wave * 128 + nf * 16 + l] = cmax[nf];
    }
    __syncthreads();
    if (t < 128) {
        float v = redf[t];
        v = fmaxf(v, redf[128 + t]);
        v = fmaxf(v, redf[256 + t]);
        v = fmaxf(v, redf[384 + t]);
        int b = blockIdx.x >> 5;  // 32 row-tiles per batch
        atomicMax(&menc[b * 512 + cb + t], fenc(v));
    }
}

// ---------------------------------------------------------------------------
// lat: grid (8 batches, 16 col-groups of 32).  lat[b][c] =
// selu(sum_k m[b][k]*w_e2[k][c] + b_e2[c]).  k split 8 ways, LDS reduce.
// ---------------------------------------------------------------------------
__global__ __launch_bounds__(256) void lat_kernel(
    const unsigned int* __restrict__ menc, const float* __restrict__ w_e2,
    const float* __restrict__ b_e2, float* __restrict__ lat) {
    int b = blockIdx.x;
    int cg = blockIdx.y;
    int t = threadIdx.x;
    __shared__ float ml[512];
    __shared__ float red[8][32];
    ml[t] = fdec(menc[b * 512 + t]);
    ml[t + 256] = fdec(menc[b * 512 + t + 256]);
    __syncthreads();
    int cl = t & 31;          // column within group
    int kg = t >> 5;          // 0..7, k-chunks of 64
    int c = cg * 32 + cl;
    const float* wp = w_e2 + (size_t)(kg * 64) * 512 + c;
    const float* mlp = ml + kg * 64;
    float acc = 0.f;
    #pragma unroll 16
    for (int k = 0; k < 64; k++) acc = fmaf(mlp[k], wp[(size_t)k * 512], acc);
    red[kg][cl] = acc;
    __syncthreads();
    if (t < 32) {
        float v = ((red[0][t] + red[1][t]) + (red[2][t] + red[3][t])) +
                  ((red[4][t] + red[5][t]) + (red[6][t] + red[7][t]));
        lat[b * 512 + cg * 32 + t] = selu_f(v + b_e2[cg * 32 + t]);
    }
}

// ---------------------------------------------------------------------------
// latw + decode (8 blocks, one per batch): latw = lat @ w_d1/w_d2[:512] +
// bias (LDS reduce), then decode the batch's 4096 points.
// ---------------------------------------------------------------------------
__global__ __launch_bounds__(256) void latw_decode_kernel(
    const float* __restrict__ lat, const float* __restrict__ w_d1,
    const float* __restrict__ b_d1, const float* __restrict__ w_d2,
    const float* __restrict__ b_d2, float* __restrict__ out) {
    int b = blockIdx.x;
    int t = threadIdx.x;
    __shared__ float ll[512];
    __shared__ float red[6][256];
    __shared__ float lw[6];
    ll[t] = lat[b * 512 + t];
    ll[t + 256] = lat[b * 512 + t + 256];
    __syncthreads();
    float p[6] = {0.f, 0.f, 0.f, 0.f, 0.f, 0.f};
    for (int k = t; k < 512; k += 256) {
        float lv = ll[k];
        #pragma unroll
        for (int j = 0; j < 3; j++) {
            p[j]     = fmaf(lv, w_d1[k * 3 + j], p[j]);
            p[3 + j] = fmaf(lv, w_d2[k * 3 + j], p[3 + j]);
        }
    }
    #pragma unroll
    for (int j = 0; j < 6; j++) red[j][t] = p[j];
    __syncthreads();
    for (int s = 128; s > 0; s >>= 1) {
        if (t < s) {
            #pragma unroll
            for (int j = 0; j < 6; j++) red[j][t] += red[j][t + s];
        }
        __syncthreads();
    }
    if (t < 3) {
        lw[t]     = red[t][0] + b_d1[t];
        lw[3 + t] = red[3 + t][0] + b_d2[t];
    }
    __syncthreads();
    float l10 = lw[0], l11 = lw[1], l12 = lw[2];
    float l20 = lw[3], l21 = lw[4], l22 = lw[5];
    float w1a0 = w_d1[1536 + 0], w1a1 = w_d1[1536 + 1], w1a2 = w_d1[1536 + 2];
    float w1b0 = w_d1[1539 + 0], w1b1 = w_d1[1539 + 1], w1b2 = w_d1[1539 + 2];
    float w2a0 = w_d2[1536 + 0], w2a1 = w_d2[1536 + 1], w2a2 = w_d2[1536 + 2];
    float w2b0 = w_d2[1539 + 0], w2b1 = w_d2[1539 + 1], w2b2 = w_d2[1539 + 2];
    float w2c0 = w_d2[1542 + 0], w2c1 = w_d2[1542 + 1], w2c2 = w_d2[1542 + 2];
    for (int n = t; n < 4096; n += 256) {
        int i = n / 46;
        int j = n - i * 46;
        float y0 = fmaf((float)i, 119.f / 90.f, 1.f);
        float y1 = fmaf((float)j, 59.f / 45.f, 1.f);
        float k0 = selu_f(l10 + y0 * w1a0 + y1 * w1b0);
        float k1 = selu_f(l11 + y0 * w1a1 + y1 * w1b1);
        float k2 = selu_f(l12 + y0 * w1a2 + y1 * w1b2);
        float o0 = selu_f(l20 + k0 * w2a0 + k1 * w2b0 + k2 * w2c0);
        float o1 = selu_f(l21 + k0 * w2a1 + k1 * w2b1 + k2 * w2c1);
        float o2 = selu_f(l22 + k0 * w2a2 + k1 * w2b2 + k2 * w2c2);
        size_t pidx = (size_t)(b * 4096 + n) * 3;
        out[pidx + 0] = o0;
        out[pidx + 1] = o1;
        out[pidx + 2] = o2;
    }
}

// ---------------------------------------------------------------------------
extern "C" void kernel_launch(void* const* d_in, const int* in_sizes, int n_in,
                              void* d_out, int out_size, void* d_ws, size_t ws_size,
                              hipStream_t stream) {
    const float* x    = (const float*)d_in[0];
    const int*   knn  = (const int*)d_in[1];
    const float* w_e1 = (const float*)d_in[2];
    const float* b_e1 = (const float*)d_in[3];
    const float* w_g1 = (const float*)d_in[4];
    const float* b_g1 = (const float*)d_in[5];
    const float* w_g2 = (const float*)d_in[6];
    const float* b_g2 = (const float*)d_in[7];
    const float* w_e2 = (const float*)d_in[8];
    const float* b_e2 = (const float*)d_in[9];
    const float* w_d1 = (const float*)d_in[10];
    const float* b_d1 = (const float*)d_in[11];
    const float* w_d2 = (const float*)d_in[12];
    const float* b_d2 = (const float*)d_in[13];
    float* out = (float*)d_out;

    const int BN = in_sizes[0] / 3;   // 32768
    const int E  = in_sizes[1] / 2;   // 524288
    const int Bb = BN / 4096;         // 8
    const int* src = knn;
    const int* dst = knn + E;

    size_t off = 0;
    auto alloc = [&](size_t bytes) -> void* {
        void* p = (char*)d_ws + off;
        off += (bytes + 255) & ~(size_t)255;
        return p;
    };
    unsigned short* hs1 = (unsigned short*)alloc((size_t)(BN + 1) * 64 * 2);
    unsigned short* hs2 = (unsigned short*)alloc((size_t)(BN + 1) * 128 * 2);
    unsigned short* a2  = (unsigned short*)alloc((size_t)BN * 128 * 2);
    unsigned short* Wp1 = (unsigned short*)alloc((size_t)16 * 64 * 8 * 2);
    unsigned short* Wp2 = (unsigned short*)alloc((size_t)128 * 64 * 8 * 2);
    unsigned int* menc = (unsigned int*)alloc((size_t)Bb * 512 * 4);
    float* lat    = (float*)alloc((size_t)Bb * 512 * 4);
    float* dinv   = (float*)alloc((size_t)BN * 4);
    int*   cnt    = (int*)alloc((size_t)BN * 4);
    int*   epos   = (int*)alloc((size_t)E * 4);
    int*   indptr = (int*)alloc((size_t)(BN + 1) * 4);
    int*   bsums  = (int*)alloc((size_t)128 * 4);
    int*   ssrc   = (int*)alloc((size_t)(E + 7 * BN + 1024) * 4);
    (void)ws_size;

    const int nb_scatter = (E + 255) / 256;  // 2048

    // prep: zero cnt + sentinel rows + m_enc, pack both weight matrices
    prep_kernel<<<273, 256, 0, stream>>>(
        cnt, (unsigned int*)(hs1 + (size_t)BN * 64),
        (unsigned int*)(hs2 + (size_t)BN * 128), menc, w_g1, Wp1, w_g2, Wp2);
    // count + per-edge slot
    count_kernel<<<(E + 255) / 256, 256, 0, stream>>>(dst, cnt, epos, E);
    scanA_kernel<<<BN / 256, 256, 0, stream>>>(cnt, bsums, dinv);
    scanC_kernel<<<BN / 256, 256, 0, stream>>>(cnt, bsums, indptr, ssrc, BN);
    // scatter || encoder
    scatter_cov_kernel<<<nb_scatter + 128, 256, 0, stream>>>(
        src, dst, epos, indptr, ssrc, E, nb_scatter,
        x, w_e1, b_e1, dinv, hs1);

    // GCN1 fused: agg(64) -> MFMA K=64 -> bf16 hs2 (dinv-prescaled)
    gcn1_kernel<<<BN / 128, 256, 0, stream>>>(hs1, dinv, indptr, ssrc, Wp1, b_g1, hs2);

    // GCN2 split: agg(128) -> MFMA + column max (atomicMax into m_enc)
    agg128_kernel<<<BN / 16, 256, 0, stream>>>(hs2, dinv, indptr, ssrc, a2, BN);
    gemm2_kernel<<<dim3(BN / 128, 4), 256, 0, stream>>>(a2, Wp2, b_g2, menc, 512);

    // latent matmul, parallel over 8x16 blocks
    lat_kernel<<<dim3(Bb, 16), 256, 0, stream>>>(menc, w_e2, b_e2, lat);

    // latw + decode (one block per batch)
    latw_decode_kernel<<<Bb, 256, 0, stream>>>(lat, w_d1, b_d1, w_d2, b_d2, out);
}

// Round 11
// 210.637 us; speedup vs baseline: 1.1896x; 1.0168x over previous
//
#include <hip/hip_runtime.h>
#include <math.h>

#define SELU_SCALE 1.0507009873554804934193349852946f
#define SELU_ALPHA 1.6732632423543772848170429916717f

typedef short bf16x8 __attribute__((ext_vector_type(8)));
typedef float f32x4 __attribute__((ext_vector_type(4)));

__device__ __forceinline__ float selu_f(float x) {
    return SELU_SCALE * (x > 0.f ? x : SELU_ALPHA * expm1f(x));
}

__device__ __forceinline__ unsigned short f2bf(float f) {
    unsigned int u = __float_as_uint(f);
    u += 0x7FFF + ((u >> 16) & 1);  // round-to-nearest-even
    return (unsigned short)(u >> 16);
}
__device__ __forceinline__ float bflo(unsigned int u) { return __uint_as_float(u << 16); }
__device__ __forceinline__ float bfhi(unsigned int u) { return __uint_as_float(u & 0xFFFF0000u); }

// monotonic float<->uint encoding (order-preserving); max in uint == max in float
__device__ __forceinline__ unsigned int fenc(float f) {
    unsigned int u = __float_as_uint(f);
    return (u & 0x80000000u) ? ~u : (u | 0x80000000u);
}
__device__ __forceinline__ float fdec(unsigned int u) {
    return __uint_as_float((u & 0x80000000u) ? (u ^ 0x80000000u) : ~u);
}

__device__ __forceinline__ void acc8(float* a, uint4 v) {
    a[0] += bflo(v.x); a[1] += bfhi(v.x);
    a[2] += bflo(v.y); a[3] += bfhi(v.y);
    a[4] += bflo(v.z); a[5] += bfhi(v.z);
    a[6] += bflo(v.w); a[7] += bfhi(v.w);
}

__device__ __forceinline__ uint4 pack8(const float* a, float dv) {
    uint4 pk;
    pk.x = (unsigned int)f2bf(a[0] * dv) | ((unsigned int)f2bf(a[1] * dv) << 16);
    pk.y = (unsigned int)f2bf(a[2] * dv) | ((unsigned int)f2bf(a[3] * dv) << 16);
    pk.z = (unsigned int)f2bf(a[4] * dv) | ((unsigned int)f2bf(a[5] * dv) << 16);
    pk.w = (unsigned int)f2bf(a[6] * dv) | ((unsigned int)f2bf(a[7] * dv) << 16);
    return pk;
}

// ---------------------------------------------------------------------------
// prep: blocks 0..127 zero cnt; block 128 zeros sentinel rows + m_enc;
// blocks 129..272 pack weights into MFMA B-fragment layout.
// ---------------------------------------------------------------------------
__global__ __launch_bounds__(256) void prep_kernel(
    int* __restrict__ cnt, unsigned int* __restrict__ pad1,
    unsigned int* __restrict__ pad2, unsigned int* __restrict__ menc,
    const float* __restrict__ W1, unsigned short* __restrict__ Wp1,
    const float* __restrict__ W2, unsigned short* __restrict__ Wp2) {
    int b = blockIdx.x;
    int t = threadIdx.x;
    if (b < 128) {
        cnt[b * 256 + t] = 0;
    } else if (b == 128) {
        if (t < 32) pad1[t] = 0;   // hs1 sentinel row (64 bf16)
        if (t < 64) pad2[t] = 0;   // hs2 sentinel row (128 bf16)
        for (int i = t; i < 4096; i += 256) menc[i] = 0u;  // enc-min
    } else {
        if (t >= 64) return;
        int fb = b - 129;
        const float* W; unsigned short* Wp; int K, N, f;
        if (fb < 16) { W = W1; Wp = Wp1; K = 64; N = 128; f = fb; }
        else         { W = W2; Wp = Wp2; K = 128; N = 512; f = fb - 16; }
        int l = t;  // 0..63
        int KS = K / 32;
        int nt = f / KS, ks = f % KS;
        int ncol = nt * 16 + (l & 15);
        int k0 = ks * 32 + (l >> 4) * 8;
        unsigned short v[8];
        #pragma unroll
        for (int j = 0; j < 8; j++) v[j] = f2bf(W[(size_t)(k0 + j) * N + ncol]);
        *(uint4*)&Wp[((size_t)f * 64 + l) * 8] = *(uint4*)v;
    }
}

// count degrees AND record each edge's slot within its destination's segment
__global__ void count_kernel(const int* __restrict__ dst, int* __restrict__ cnt,
                             int* __restrict__ epos, int E) {
    int e = blockIdx.x * blockDim.x + threadIdx.x;
    if (e < E) epos[e] = atomicAdd(&cnt[dst[e]], 1);
}

// --- parallel exclusive scan over padded counts ((c+7)&~7) ---
__global__ __launch_bounds__(256) void scanA_kernel(const int* __restrict__ cnt,
                                                    int* __restrict__ blockSums,
                                                    float* __restrict__ dinv) {
    __shared__ int red[256];
    int t = threadIdx.x;
    int i = blockIdx.x * 256 + t;
    int c = cnt[i];
    dinv[i] = rsqrtf((float)(c + 1));
    red[t] = (c + 7) & ~7;
    __syncthreads();
    for (int s = 128; s > 0; s >>= 1) {
        if (t < s) red[t] += red[t + s];
        __syncthreads();
    }
    if (t == 0) blockSums[blockIdx.x] = red[0];
}

__global__ __launch_bounds__(256) void scanC_kernel(
    const int* __restrict__ cnt, const int* __restrict__ bsums,
    int* __restrict__ indptr, int* __restrict__ ssrc, int n) {
    __shared__ int sc[256];
    __shared__ int bs[128];
    int t = threadIdx.x;
    int ownSum = bsums[blockIdx.x];
    if (t < 128) bs[t] = bsums[t];
    int i = blockIdx.x * 256 + t;
    int c = cnt[i];
    int pc = (c + 7) & ~7;
    sc[t] = pc;
    __syncthreads();
    for (int off = 1; off < 128; off <<= 1) {
        int v = (t >= off && t < 128) ? bs[t - off] : 0;
        __syncthreads();
        if (t < 128) bs[t] += v;
        __syncthreads();
    }
    for (int off = 1; off < 256; off <<= 1) {
        int v = t >= off ? sc[t - off] : 0;
        __syncthreads();
        sc[t] += v;
        __syncthreads();
    }
    int blockOff = bs[blockIdx.x] - ownSum;  // exclusive block offset
    int ip = blockOff + sc[t] - pc;          // exclusive elem offset
    indptr[i] = ip;
    for (int k = c; k < pc; k++) ssrc[ip + k] = n;  // sentinel zero-row
    if (i == n - 1) indptr[n] = blockOff + sc[t];
}

// ---------------------------------------------------------------------------
// scatter (blocks 0..nb_scatter-1) || cov_enc (remaining 128 blocks).
// ---------------------------------------------------------------------------
__global__ __launch_bounds__(256) void scatter_cov_kernel(
    const int* __restrict__ src, const int* __restrict__ dst,
    const int* __restrict__ epos, const int* __restrict__ indptr,
    int* __restrict__ ssrc, int E, int nb_scatter,
    const float* __restrict__ x, const float* __restrict__ w_e1,
    const float* __restrict__ b_e1, const float* __restrict__ dinv,
    unsigned short* __restrict__ hs1) {
    int t = threadIdx.x;
    if ((int)blockIdx.x < nb_scatter) {
        int e = blockIdx.x * 256 + t;
        if (e < E) ssrc[indptr[dst[e]] + epos[e]] = src[e];
        return;
    }
    // ---- cov_enc part ----
    __shared__ float Wl[12 * 64];
    __shared__ float Bl[64];
    __shared__ float xs[280 * 3];
    int cb = blockIdx.x - nb_scatter;  // 0..127
    for (int i = t; i < 768; i += 256) Wl[i] = w_e1[i];
    if (t < 64) Bl[t] = b_e1[t];
    int p0 = cb * 256;
    int n0 = p0 & 4095;
    const float* xb = x + (size_t)(p0 - n0) * 3;  // batch base (256 | 4096)
    for (int idx = t; idx < 840; idx += 256) {
        int slot = idx / 3, d = idx - slot * 3;
        int g = n0 - 12 + slot;
        g = g < 0 ? 0 : (g > 4095 ? 4095 : g);
        xs[idx] = xb[g * 3 + d];
    }
    __syncthreads();
    int p = p0 + t;
    int n = n0 + t;
    int lo = n - 12 < 0 ? 0 : n - 12;
    int hi = n + 12 > 4095 ? 4095 : n + 12;
    int slo = lo - n0 + 12, shi = hi - n0 + 12;
    float sx = 0.f, sy = 0.f, sz = 0.f;
    float sxx = 0.f, sxy = 0.f, sxz = 0.f, syy = 0.f, syz = 0.f, szz = 0.f;
    for (int s = slo; s <= shi; s++) {
        float xv = xs[s * 3 + 0], yv = xs[s * 3 + 1], zv = xs[s * 3 + 2];
        sx += xv; sy += yv; sz += zv;
        sxx = fmaf(xv, xv, sxx); sxy = fmaf(xv, yv, sxy); sxz = fmaf(xv, zv, sxz);
        syy = fmaf(yv, yv, syy); syz = fmaf(yv, zv, syz); szz = fmaf(zv, zv, szz);
    }
    float cntf = (float)(shi - slo + 1);
    float rin = 1.f / cntf;
    float mx = sx * rin, my = sy * rin, mz = sz * rin;
    const float inv23 = 1.f / 23.f;
    float c00 = (sxx - sx * mx) * inv23;
    float c01 = (sxy - sx * my) * inv23;
    float c02 = (sxz - sx * mz) * inv23;
    float c11 = (syy - sy * my) * inv23;
    float c12 = (syz - sy * mz) * inv23;
    float c22 = (szz - sz * mz) * inv23;
    float feat[12];
    feat[0] = xs[(t + 12) * 3 + 0];
    feat[1] = xs[(t + 12) * 3 + 1];
    feat[2] = xs[(t + 12) * 3 + 2];
    feat[3] = c00; feat[4] = c01; feat[5]  = c02;
    feat[6] = c01; feat[7] = c11; feat[8]  = c12;
    feat[9] = c02; feat[10] = c12; feat[11] = c22;
    float dv = dinv[p];
    unsigned int* hp = (unsigned int*)(hs1 + (size_t)p * 64);
    for (int c = 0; c < 64; c += 2) {
        float a0 = Bl[c], a1 = Bl[c + 1];
        #pragma unroll
        for (int i = 0; i < 12; i++) {
            a0 = fmaf(feat[i], Wl[i * 64 + c], a0);
            a1 = fmaf(feat[i], Wl[i * 64 + c + 1], a1);
        }
        unsigned int pk = (unsigned int)f2bf(dv * selu_f(a0)) |
                          ((unsigned int)f2bf(dv * selu_f(a1)) << 16);
        hp[c >> 1] = pk;
    }
}

// ---------------------------------------------------------------------------
// Fused GCN1: aggregate 128 nodes (C=64) into LDS, MFMA K=64 N=128,
// write bf16 hs2 (dinv-prescaled).
// ---------------------------------------------------------------------------
__global__ __launch_bounds__(256) void gcn1_kernel(
    const unsigned short* __restrict__ hs1, const float* __restrict__ dinv,
    const int* __restrict__ indptr, const int* __restrict__ ssrc,
    const unsigned short* __restrict__ Wp, const float* __restrict__ bias,
    unsigned short* __restrict__ hs2) {
    constexpr int LDA = 72;  // 64 + 8 bf16 pad
    __shared__ unsigned short As[128 * LDA];
    int t = threadIdx.x;
    int R0 = blockIdx.x * 128;
    const uint4* hp = (const uint4*)hs1;

    for (int idx = t; idx < 1024; idx += 256) {
        int nl = idx >> 3, cq = idx & 7;
        int node = R0 + nl;
        float a[8];
        {
            uint4 u = hp[(size_t)node * 8 + cq];
            a[0] = bflo(u.x); a[1] = bfhi(u.x);
            a[2] = bflo(u.y); a[3] = bfhi(u.y);
            a[4] = bflo(u.z); a[5] = bfhi(u.z);
            a[6] = bflo(u.w); a[7] = bfhi(u.w);
        }
        int beg = indptr[node], end = indptr[node + 1];
        for (int j = beg; j < end; j += 8) {
            int s[8];
            #pragma unroll
            for (int q = 0; q < 8; q++) s[q] = ssrc[j + q];
            uint4 v[8];
            #pragma unroll
            for (int q = 0; q < 8; q++) v[q] = hp[(size_t)s[q] * 8 + cq];
            #pragma unroll
            for (int q = 0; q < 8; q++) acc8(a, v[q]);
        }
        *(uint4*)&As[nl * LDA + cq * 8] = pack8(a, dinv[node]);
    }
    __syncthreads();

    int wave = t >> 6, l = t & 63;
    int ml = l & 15, q = l >> 4;
    int wr = wave * 32;
    f32x4 acc[2][8];
    #pragma unroll
    for (int mf = 0; mf < 2; mf++)
        #pragma unroll
        for (int nf = 0; nf < 8; nf++) acc[mf][nf] = (f32x4){0.f, 0.f, 0.f, 0.f};
    const bf16x8* wp8 = (const bf16x8*)Wp;
    #pragma unroll
    for (int ks = 0; ks < 2; ks++) {
        bf16x8 af[2];
        #pragma unroll
        for (int mf = 0; mf < 2; mf++)
            af[mf] = *(const bf16x8*)&As[(wr + mf * 16 + ml) * LDA + ks * 32 + q * 8];
        bf16x8 bfr[8];
        #pragma unroll
        for (int nf = 0; nf < 8; nf++)
            bfr[nf] = wp8[(size_t)(nf * 2 + ks) * 64 + l];
        #pragma unroll
        for (int mf = 0; mf < 2; mf++)
            #pragma unroll
            for (int nf = 0; nf < 8; nf++)
                acc[mf][nf] = __builtin_amdgcn_mfma_f32_16x16x32_bf16(
                    af[mf], bfr[nf], acc[mf][nf], 0, 0, 0);
    }
    float bj[8];
    #pragma unroll
    for (int nf = 0; nf < 8; nf++) bj[nf] = bias[nf * 16 + ml];
    #pragma unroll
    for (int mf = 0; mf < 2; mf++) {
        #pragma unroll
        for (int r = 0; r < 4; r++) {
            int row = R0 + wr + mf * 16 + q * 4 + r;
            float dv = dinv[row];
            #pragma unroll
            for (int nf = 0; nf < 8; nf++) {
                float v = dv * selu_f(acc[mf][nf][r] + bj[nf]);
                hs2[(size_t)row * 128 + nf * 16 + ml] = f2bf(v);
            }
        }
    }
}

// ---------------------------------------------------------------------------
// Aggregation (C=128), standalone for max occupancy (latency-bound gather).
// ---------------------------------------------------------------------------
__global__ __launch_bounds__(256) void agg128_kernel(
    const unsigned short* __restrict__ hs, const float* __restrict__ dinv,
    const int* __restrict__ indptr, const int* __restrict__ ssrc,
    unsigned short* __restrict__ out, int n_nodes) {
    constexpr int TPN = 16;
    int node = blockIdx.x * (256 / TPN) + threadIdx.x / TPN;
    int cq = threadIdx.x % TPN;
    if (node >= n_nodes) return;
    const uint4* hp = (const uint4*)hs;
    float a[8];
    {
        uint4 u = hp[(size_t)node * TPN + cq];
        a[0] = bflo(u.x); a[1] = bfhi(u.x);
        a[2] = bflo(u.y); a[3] = bfhi(u.y);
        a[4] = bflo(u.z); a[5] = bfhi(u.z);
        a[6] = bflo(u.w); a[7] = bfhi(u.w);
    }
    int beg = indptr[node], end = indptr[node + 1];
    for (int j = beg; j < end; j += 8) {
        int s[8];
        #pragma unroll
        for (int q = 0; q < 8; q++) s[q] = ssrc[j + q];
        uint4 v[8];
        #pragma unroll
        for (int q = 0; q < 8; q++) v[q] = hp[(size_t)s[q] * TPN + cq];
        #pragma unroll
        for (int q = 0; q < 8; q++) acc8(a, v[q]);
    }
    ((uint4*)out)[(size_t)node * TPN + cq] = pack8(a, dinv[node]);
}

// ---------------------------------------------------------------------------
// MFMA bf16 GEMM (K=128): selu + column max -> atomicMax into m_enc (exact).
// ---------------------------------------------------------------------------
__global__ __launch_bounds__(256) void gemm2_kernel(
    const unsigned short* __restrict__ A, const unsigned short* __restrict__ Wp,
    const float* __restrict__ bias, unsigned int* __restrict__ menc, int Nfull) {
    constexpr int KS = 4;
    constexpr int LDA = 136;  // 128 + 8
    constexpr int CPR = 16;
    __shared__ unsigned short As[128 * LDA];
    int t = threadIdx.x;
    int wave = t >> 6, l = t & 63;
    int ml = l & 15, q = l >> 4;
    int R0 = blockIdx.x * 128;
    int cb = blockIdx.y * 128;

    for (int c = t; c < 128 * CPR; c += 256) {
        int row = c / CPR, off = c % CPR;
        *(uint4*)&As[row * LDA + off * 8] =
            *(const uint4*)&A[(size_t)(R0 + row) * 128 + off * 8];
    }
    __syncthreads();

    f32x4 acc[2][8];
    #pragma unroll
    for (int mf = 0; mf < 2; mf++)
        #pragma unroll
        for (int nf = 0; nf < 8; nf++) acc[mf][nf] = (f32x4){0.f, 0.f, 0.f, 0.f};

    const bf16x8* wp8 = (const bf16x8*)Wp;
    int wr = wave * 32;
    #pragma unroll
    for (int ks = 0; ks < KS; ks++) {
        bf16x8 af[2];
        #pragma unroll
        for (int mf = 0; mf < 2; mf++)
            af[mf] = *(const bf16x8*)&As[(wr + mf * 16 + ml) * LDA + ks * 32 + q * 8];
        bf16x8 bfr[8];
        #pragma unroll
        for (int nf = 0; nf < 8; nf++)
            bfr[nf] = wp8[(size_t)(((cb >> 4) + nf) * KS + ks) * 64 + l];
        #pragma unroll
        for (int mf = 0; mf < 2; mf++)
            #pragma unroll
            for (int nf = 0; nf < 8; nf++)
                acc[mf][nf] = __builtin_amdgcn_mfma_f32_16x16x32_bf16(
                    af[mf], bfr[nf], acc[mf][nf], 0, 0, 0);
    }

    // selu + column max; C/D layout: col = ml, row = q*4 + r
    float cmax[8];
    #pragma unroll
    for (int nf = 0; nf < 8; nf++) {
        float bj = bias[cb + nf * 16 + ml];
        float v = -INFINITY;
        #pragma unroll
        for (int mf = 0; mf < 2; mf++)
            #pragma unroll
            for (int r = 0; r < 4; r++)
                v = fmaxf(v, selu_f(acc[mf][nf][r] + bj));
        v = fmaxf(v, __shfl_xor(v, 16, 64));
        v = fmaxf(v, __shfl_xor(v, 32, 64));
        cmax[nf] = v;
    }
    __syncthreads();  // before reusing As as f32 scratch
    float* redf = (float*)As;  // [4 waves][128 cols]
    if (ml == l) {  // lanes 0..15
        #pragma unroll
        for (int nf = 0; nf < 8; nf++) redf[wave * 128 + nf * 16 + l] = cmax[nf];
    }
    __syncthreads();
    if (t < 128) {
        float v = redf[t];
        v = fmaxf(v, redf[128 + t]);
        v = fmaxf(v, redf[256 + t]);
        v = fmaxf(v, redf[384 + t]);
        int b = blockIdx.x >> 5;  // 32 row-tiles per batch
        atomicMax(&menc[b * 512 + cb + t], fenc(v));
    }
}

// ---------------------------------------------------------------------------
// lat: grid (8 batches, 16 col-groups of 32).  lat[b][c] =
// selu(sum_k m[b][k]*w_e2[k][c] + b_e2[c]).  k split 8 ways, LDS reduce.
// ---------------------------------------------------------------------------
__global__ __launch_bounds__(256) void lat_kernel(
    const unsigned int* __restrict__ menc, const float* __restrict__ w_e2,
    const float* __restrict__ b_e2, float* __restrict__ lat) {
    int b = blockIdx.x;
    int cg = blockIdx.y;
    int t = threadIdx.x;
    __shared__ float ml[512];
    __shared__ float red[8][32];
    ml[t] = fdec(menc[b * 512 + t]);
    ml[t + 256] = fdec(menc[b * 512 + t + 256]);
    __syncthreads();
    int cl = t & 31;          // column within group
    int kg = t >> 5;          // 0..7, k-chunks of 64
    int c = cg * 32 + cl;
    const float* wp = w_e2 + (size_t)(kg * 64) * 512 + c;
    const float* mlp = ml + kg * 64;
    float acc = 0.f;
    #pragma unroll 16
    for (int k = 0; k < 64; k++) acc = fmaf(mlp[k], wp[(size_t)k * 512], acc);
    red[kg][cl] = acc;
    __syncthreads();
    if (t < 32) {
        float v = ((red[0][t] + red[1][t]) + (red[2][t] + red[3][t])) +
                  ((red[4][t] + red[5][t]) + (red[6][t] + red[7][t]));
        lat[b * 512 + cg * 32 + t] = selu_f(v + b_e2[cg * 32 + t]);
    }
}

// ---------------------------------------------------------------------------
// latw + decode: 64 blocks = 8 batches x 8 point-slices.  Each block
// recomputes the tiny latw reduction (512x6) then decodes its 512 points.
// ---------------------------------------------------------------------------
__global__ __launch_bounds__(256) void latw_decode_kernel(
    const float* __restrict__ lat, const float* __restrict__ w_d1,
    const float* __restrict__ b_d1, const float* __restrict__ w_d2,
    const float* __restrict__ b_d2, float* __restrict__ out) {
    int b = blockIdx.x >> 3;   // batch
    int sl = blockIdx.x & 7;   // point slice
    int t = threadIdx.x;
    __shared__ float ll[512];
    __shared__ float red[6][256];
    __shared__ float lw[6];
    ll[t] = lat[b * 512 + t];
    ll[t + 256] = lat[b * 512 + t + 256];
    __syncthreads();
    float p[6] = {0.f, 0.f, 0.f, 0.f, 0.f, 0.f};
    for (int k = t; k < 512; k += 256) {
        float lv = ll[k];
        #pragma unroll
        for (int j = 0; j < 3; j++) {
            p[j]     = fmaf(lv, w_d1[k * 3 + j], p[j]);
            p[3 + j] = fmaf(lv, w_d2[k * 3 + j], p[3 + j]);
        }
    }
    #pragma unroll
    for (int j = 0; j < 6; j++) red[j][t] = p[j];
    __syncthreads();
    for (int s = 128; s > 0; s >>= 1) {
        if (t < s) {
            #pragma unroll
            for (int j = 0; j < 6; j++) red[j][t] += red[j][t + s];
        }
        __syncthreads();
    }
    if (t < 3) {
        lw[t]     = red[t][0] + b_d1[t];
        lw[3 + t] = red[3 + t][0] + b_d2[t];
    }
    __syncthreads();
    float l10 = lw[0], l11 = lw[1], l12 = lw[2];
    float l20 = lw[3], l21 = lw[4], l22 = lw[5];
    float w1a0 = w_d1[1536 + 0], w1a1 = w_d1[1536 + 1], w1a2 = w_d1[1536 + 2];
    float w1b0 = w_d1[1539 + 0], w1b1 = w_d1[1539 + 1], w1b2 = w_d1[1539 + 2];
    float w2a0 = w_d2[1536 + 0], w2a1 = w_d2[1536 + 1], w2a2 = w_d2[1536 + 2];
    float w2b0 = w_d2[1539 + 0], w2b1 = w_d2[1539 + 1], w2b2 = w_d2[1539 + 2];
    float w2c0 = w_d2[1542 + 0], w2c1 = w_d2[1542 + 1], w2c2 = w_d2[1542 + 2];
    {
        int n = sl * 512 + t;        // first 256 of the slice
        #pragma unroll
        for (int half = 0; half < 2; half++) {
            int i = n / 46;
            int j = n - i * 46;
            float y0 = fmaf((float)i, 119.f / 90.f, 1.f);
            float y1 = fmaf((float)j, 59.f / 45.f, 1.f);
            float k0 = selu_f(l10 + y0 * w1a0 + y1 * w1b0);
            float k1 = selu_f(l11 + y0 * w1a1 + y1 * w1b1);
            float k2 = selu_f(l12 + y0 * w1a2 + y1 * w1b2);
            float o0 = selu_f(l20 + k0 * w2a0 + k1 * w2b0 + k2 * w2c0);
            float o1 = selu_f(l21 + k0 * w2a1 + k1 * w2b1 + k2 * w2c1);
            float o2 = selu_f(l22 + k0 * w2a2 + k1 * w2b2 + k2 * w2c2);
            size_t pidx = (size_t)(b * 4096 + n) * 3;
            out[pidx + 0] = o0;
            out[pidx + 1] = o1;
            out[pidx + 2] = o2;
            n += 256;
        }
    }
}

// ---------------------------------------------------------------------------
extern "C" void kernel_launch(void* const* d_in, const int* in_sizes, int n_in,
                              void* d_out, int out_size, void* d_ws, size_t ws_size,
                              hipStream_t stream) {
    const float* x    = (const float*)d_in[0];
    const int*   knn  = (const int*)d_in[1];
    const float* w_e1 = (const float*)d_in[2];
    const float* b_e1 = (const float*)d_in[3];
    const float* w_g1 = (const float*)d_in[4];
    const float* b_g1 = (const float*)d_in[5];
    const float* w_g2 = (const float*)d_in[6];
    const float* b_g2 = (const float*)d_in[7];
    const float* w_e2 = (const float*)d_in[8];
    const float* b_e2 = (const float*)d_in[9];
    const float* w_d1 = (const float*)d_in[10];
    const float* b_d1 = (const float*)d_in[11];
    const float* w_d2 = (const float*)d_in[12];
    const float* b_d2 = (const float*)d_in[13];
    float* out = (float*)d_out;

    const int BN = in_sizes[0] / 3;   // 32768
    const int E  = in_sizes[1] / 2;   // 524288
    const int Bb = BN / 4096;         // 8
    const int* src = knn;
    const int* dst = knn + E;

    size_t off = 0;
    auto alloc = [&](size_t bytes) -> void* {
        void* p = (char*)d_ws + off;
        off += (bytes + 255) & ~(size_t)255;
        return p;
    };
    unsigned short* hs1 = (unsigned short*)alloc((size_t)(BN + 1) * 64 * 2);
    unsigned short* hs2 = (unsigned short*)alloc((size_t)(BN + 1) * 128 * 2);
    unsigned short* a2  = (unsigned short*)alloc((size_t)BN * 128 * 2);
    unsigned short* Wp1 = (unsigned short*)alloc((size_t)16 * 64 * 8 * 2);
    unsigned short* Wp2 = (unsigned short*)alloc((size_t)128 * 64 * 8 * 2);
    unsigned int* menc = (unsigned int*)alloc((size_t)Bb * 512 * 4);
    float* lat    = (float*)alloc((size_t)Bb * 512 * 4);
    float* dinv   = (float*)alloc((size_t)BN * 4);
    int*   cnt    = (int*)alloc((size_t)BN * 4);
    int*   epos   = (int*)alloc((size_t)E * 4);
    int*   indptr = (int*)alloc((size_t)(BN + 1) * 4);
    int*   bsums  = (int*)alloc((size_t)128 * 4);
    int*   ssrc   = (int*)alloc((size_t)(E + 7 * BN + 1024) * 4);
    (void)ws_size;

    const int nb_scatter = (E + 255) / 256;  // 2048

    // prep: zero cnt + sentinel rows + m_enc, pack both weight matrices
    prep_kernel<<<273, 256, 0, stream>>>(
        cnt, (unsigned int*)(hs1 + (size_t)BN * 64),
        (unsigned int*)(hs2 + (size_t)BN * 128), menc, w_g1, Wp1, w_g2, Wp2);
    // count + per-edge slot
    count_kernel<<<(E + 255) / 256, 256, 0, stream>>>(dst, cnt, epos, E);
    scanA_kernel<<<BN / 256, 256, 0, stream>>>(cnt, bsums, dinv);
    scanC_kernel<<<BN / 256, 256, 0, stream>>>(cnt, bsums, indptr, ssrc, BN);
    // scatter || encoder
    scatter_cov_kernel<<<nb_scatter + 128, 256, 0, stream>>>(
        src, dst, epos, indptr, ssrc, E, nb_scatter,
        x, w_e1, b_e1, dinv, hs1);

    // GCN1 fused: agg(64) -> MFMA K=64 -> bf16 hs2 (dinv-prescaled)
    gcn1_kernel<<<BN / 128, 256, 0, stream>>>(hs1, dinv, indptr, ssrc, Wp1, b_g1, hs2);

    // GCN2 split: agg(128) -> MFMA + column max (atomicMax into m_enc)
    agg128_kernel<<<BN / 16, 256, 0, stream>>>(hs2, dinv, indptr, ssrc, a2, BN);
    gemm2_kernel<<<dim3(BN / 128, 4), 256, 0, stream>>>(a2, Wp2, b_g2, menc, 512);

    // latent matmul, parallel over 8x16 blocks
    lat_kernel<<<dim3(Bb, 16), 256, 0, stream>>>(menc, w_e2, b_e2, lat);

    // latw + decode (64 blocks: 8 batches x 8 slices)
    latw_decode_kernel<<<Bb * 8, 256, 0, stream>>>(lat, w_d1, b_d1, w_d2, b_d2, out);
}

// Round 12
// 205.977 us; speedup vs baseline: 1.2165x; 1.0226x over previous
//
#include <hip/hip_runtime.h>
#include <math.h>

#define SELU_SCALE 1.0507009873554804934193349852946f
#define SELU_ALPHA 1.6732632423543772848170429916717f

typedef short bf16x8 __attribute__((ext_vector_type(8)));
typedef float f32x4 __attribute__((ext_vector_type(4)));

__device__ __forceinline__ float selu_f(float x) {
    return SELU_SCALE * (x > 0.f ? x : SELU_ALPHA * expm1f(x));
}

__device__ __forceinline__ unsigned short f2bf(float f) {
    unsigned int u = __float_as_uint(f);
    u += 0x7FFF + ((u >> 16) & 1);  // round-to-nearest-even
    return (unsigned short)(u >> 16);
}
__device__ __forceinline__ float bflo(unsigned int u) { return __uint_as_float(u << 16); }
__device__ __forceinline__ float bfhi(unsigned int u) { return __uint_as_float(u & 0xFFFF0000u); }

// monotonic float<->uint encoding (order-preserving); max in uint == max in float
__device__ __forceinline__ unsigned int fenc(float f) {
    unsigned int u = __float_as_uint(f);
    return (u & 0x80000000u) ? ~u : (u | 0x80000000u);
}
__device__ __forceinline__ float fdec(unsigned int u) {
    return __uint_as_float((u & 0x80000000u) ? (u ^ 0x80000000u) : ~u);
}

__device__ __forceinline__ void acc8(float* a, uint4 v) {
    a[0] += bflo(v.x); a[1] += bfhi(v.x);
    a[2] += bflo(v.y); a[3] += bfhi(v.y);
    a[4] += bflo(v.z); a[5] += bfhi(v.z);
    a[6] += bflo(v.w); a[7] += bfhi(v.w);
}

__device__ __forceinline__ uint4 pack8(const float* a, float dv) {
    uint4 pk;
    pk.x = (unsigned int)f2bf(a[0] * dv) | ((unsigned int)f2bf(a[1] * dv) << 16);
    pk.y = (unsigned int)f2bf(a[2] * dv) | ((unsigned int)f2bf(a[3] * dv) << 16);
    pk.z = (unsigned int)f2bf(a[4] * dv) | ((unsigned int)f2bf(a[5] * dv) << 16);
    pk.w = (unsigned int)f2bf(a[6] * dv) | ((unsigned int)f2bf(a[7] * dv) << 16);
    return pk;
}

// ---------------------------------------------------------------------------
// prep: blocks 0..127 zero cnt; block 128 zeros sentinel rows + m_enc;
// blocks 129..272 pack weights into MFMA B-fragment layout.
// ---------------------------------------------------------------------------
__global__ __launch_bounds__(256) void prep_kernel(
    int* __restrict__ cnt, unsigned int* __restrict__ pad1,
    unsigned int* __restrict__ pad2, unsigned int* __restrict__ menc,
    const float* __restrict__ W1, unsigned short* __restrict__ Wp1,
    const float* __restrict__ W2, unsigned short* __restrict__ Wp2) {
    int b = blockIdx.x;
    int t = threadIdx.x;
    if (b < 128) {
        cnt[b * 256 + t] = 0;
    } else if (b == 128) {
        if (t < 32) pad1[t] = 0;   // hs1 sentinel row (64 bf16)
        if (t < 64) pad2[t] = 0;   // hs2 sentinel row (128 bf16)
        for (int i = t; i < 4096; i += 256) menc[i] = 0u;  // enc-min
    } else {
        if (t >= 64) return;
        int fb = b - 129;
        const float* W; unsigned short* Wp; int K, N, f;
        if (fb < 16) { W = W1; Wp = Wp1; K = 64; N = 128; f = fb; }
        else         { W = W2; Wp = Wp2; K = 128; N = 512; f = fb - 16; }
        int l = t;  // 0..63
        int KS = K / 32;
        int nt = f / KS, ks = f % KS;
        int ncol = nt * 16 + (l & 15);
        int k0 = ks * 32 + (l >> 4) * 8;
        unsigned short v[8];
        #pragma unroll
        for (int j = 0; j < 8; j++) v[j] = f2bf(W[(size_t)(k0 + j) * N + ncol]);
        *(uint4*)&Wp[((size_t)f * 64 + l) * 8] = *(uint4*)v;
    }
}

// count degrees AND record each edge's slot within its destination's segment
__global__ void count_kernel(const int* __restrict__ dst, int* __restrict__ cnt,
                             int* __restrict__ epos, int E) {
    int e = blockIdx.x * blockDim.x + threadIdx.x;
    if (e < E) epos[e] = atomicAdd(&cnt[dst[e]], 1);
}

// --- parallel exclusive scan over padded counts ((c+7)&~7) ---
__global__ __launch_bounds__(256) void scanA_kernel(const int* __restrict__ cnt,
                                                    int* __restrict__ blockSums,
                                                    float* __restrict__ dinv) {
    __shared__ int red[256];
    int t = threadIdx.x;
    int i = blockIdx.x * 256 + t;
    int c = cnt[i];
    dinv[i] = rsqrtf((float)(c + 1));
    red[t] = (c + 7) & ~7;
    __syncthreads();
    for (int s = 128; s > 0; s >>= 1) {
        if (t < s) red[t] += red[t + s];
        __syncthreads();
    }
    if (t == 0) blockSums[blockIdx.x] = red[0];
}

__global__ __launch_bounds__(256) void scanC_kernel(
    const int* __restrict__ cnt, const int* __restrict__ bsums,
    int* __restrict__ indptr, int* __restrict__ ssrc, int n) {
    __shared__ int sc[256];
    __shared__ int bs[128];
    int t = threadIdx.x;
    int ownSum = bsums[blockIdx.x];
    if (t < 128) bs[t] = bsums[t];
    int i = blockIdx.x * 256 + t;
    int c = cnt[i];
    int pc = (c + 7) & ~7;
    sc[t] = pc;
    __syncthreads();
    for (int off = 1; off < 128; off <<= 1) {
        int v = (t >= off && t < 128) ? bs[t - off] : 0;
        __syncthreads();
        if (t < 128) bs[t] += v;
        __syncthreads();
    }
    for (int off = 1; off < 256; off <<= 1) {
        int v = t >= off ? sc[t - off] : 0;
        __syncthreads();
        sc[t] += v;
        __syncthreads();
    }
    int blockOff = bs[blockIdx.x] - ownSum;  // exclusive block offset
    int ip = blockOff + sc[t] - pc;          // exclusive elem offset
    indptr[i] = ip;
    for (int k = c; k < pc; k++) ssrc[ip + k] = n;  // sentinel zero-row
    if (i == n - 1) indptr[n] = blockOff + sc[t];
}

// ---------------------------------------------------------------------------
// scatter (blocks 0..nb_scatter-1) || cov_enc (remaining 128 blocks).
// ---------------------------------------------------------------------------
__global__ __launch_bounds__(256) void scatter_cov_kernel(
    const int* __restrict__ src, const int* __restrict__ dst,
    const int* __restrict__ epos, const int* __restrict__ indptr,
    int* __restrict__ ssrc, int E, int nb_scatter,
    const float* __restrict__ x, const float* __restrict__ w_e1,
    const float* __restrict__ b_e1, const float* __restrict__ dinv,
    unsigned short* __restrict__ hs1) {
    int t = threadIdx.x;
    if ((int)blockIdx.x < nb_scatter) {
        int e = blockIdx.x * 256 + t;
        if (e < E) ssrc[indptr[dst[e]] + epos[e]] = src[e];
        return;
    }
    // ---- cov_enc part ----
    __shared__ float Wl[12 * 64];
    __shared__ float Bl[64];
    __shared__ float xs[280 * 3];
    int cb = blockIdx.x - nb_scatter;  // 0..127
    for (int i = t; i < 768; i += 256) Wl[i] = w_e1[i];
    if (t < 64) Bl[t] = b_e1[t];
    int p0 = cb * 256;
    int n0 = p0 & 4095;
    const float* xb = x + (size_t)(p0 - n0) * 3;  // batch base (256 | 4096)
    for (int idx = t; idx < 840; idx += 256) {
        int slot = idx / 3, d = idx - slot * 3;
        int g = n0 - 12 + slot;
        g = g < 0 ? 0 : (g > 4095 ? 4095 : g);
        xs[idx] = xb[g * 3 + d];
    }
    __syncthreads();
    int p = p0 + t;
    int n = n0 + t;
    int lo = n - 12 < 0 ? 0 : n - 12;
    int hi = n + 12 > 4095 ? 4095 : n + 12;
    int slo = lo - n0 + 12, shi = hi - n0 + 12;
    float sx = 0.f, sy = 0.f, sz = 0.f;
    float sxx = 0.f, sxy = 0.f, sxz = 0.f, syy = 0.f, syz = 0.f, szz = 0.f;
    for (int s = slo; s <= shi; s++) {
        float xv = xs[s * 3 + 0], yv = xs[s * 3 + 1], zv = xs[s * 3 + 2];
        sx += xv; sy += yv; sz += zv;
        sxx = fmaf(xv, xv, sxx); sxy = fmaf(xv, yv, sxy); sxz = fmaf(xv, zv, sxz);
        syy = fmaf(yv, yv, syy); syz = fmaf(yv, zv, syz); szz = fmaf(zv, zv, szz);
    }
    float cntf = (float)(shi - slo + 1);
    float rin = 1.f / cntf;
    float mx = sx * rin, my = sy * rin, mz = sz * rin;
    const float inv23 = 1.f / 23.f;
    float c00 = (sxx - sx * mx) * inv23;
    float c01 = (sxy - sx * my) * inv23;
    float c02 = (sxz - sx * mz) * inv23;
    float c11 = (syy - sy * my) * inv23;
    float c12 = (syz - sy * mz) * inv23;
    float c22 = (szz - sz * mz) * inv23;
    float feat[12];
    feat[0] = xs[(t + 12) * 3 + 0];
    feat[1] = xs[(t + 12) * 3 + 1];
    feat[2] = xs[(t + 12) * 3 + 2];
    feat[3] = c00; feat[4] = c01; feat[5]  = c02;
    feat[6] = c01; feat[7] = c11; feat[8]  = c12;
    feat[9] = c02; feat[10] = c12; feat[11] = c22;
    float dv = dinv[p];
    unsigned int* hp = (unsigned int*)(hs1 + (size_t)p * 64);
    for (int c = 0; c < 64; c += 2) {
        float a0 = Bl[c], a1 = Bl[c + 1];
        #pragma unroll
        for (int i = 0; i < 12; i++) {
            a0 = fmaf(feat[i], Wl[i * 64 + c], a0);
            a1 = fmaf(feat[i], Wl[i * 64 + c + 1], a1);
        }
        unsigned int pk = (unsigned int)f2bf(dv * selu_f(a0)) |
                          ((unsigned int)f2bf(dv * selu_f(a1)) << 16);
        hp[c >> 1] = pk;
    }
}

// ---------------------------------------------------------------------------
// Aggregation (templated C), standalone for max occupancy: out[d] =
// dinv[d]*(hs[d] + sum hs[s]), 8 channels (uint4) per thread, 8-deep batching.
// C=64: TPN=8, 32 nodes/block, 1024 blocks.  C=128: TPN=16, 2048 blocks.
// ---------------------------------------------------------------------------
template <int C>
__global__ __launch_bounds__(256) void agg_kernel(
    const unsigned short* __restrict__ hs, const float* __restrict__ dinv,
    const int* __restrict__ indptr, const int* __restrict__ ssrc,
    unsigned short* __restrict__ out, int n_nodes) {
    constexpr int TPN = C / 8;
    int node = blockIdx.x * (256 / TPN) + threadIdx.x / TPN;
    int cq = threadIdx.x % TPN;
    if (node >= n_nodes) return;
    const uint4* hp = (const uint4*)hs;
    float a[8];
    {
        uint4 u = hp[(size_t)node * TPN + cq];
        a[0] = bflo(u.x); a[1] = bfhi(u.x);
        a[2] = bflo(u.y); a[3] = bfhi(u.y);
        a[4] = bflo(u.z); a[5] = bfhi(u.z);
        a[6] = bflo(u.w); a[7] = bfhi(u.w);
    }
    int beg = indptr[node], end = indptr[node + 1];
    for (int j = beg; j < end; j += 8) {
        int s[8];
        #pragma unroll
        for (int q = 0; q < 8; q++) s[q] = ssrc[j + q];
        uint4 v[8];
        #pragma unroll
        for (int q = 0; q < 8; q++) v[q] = hp[(size_t)s[q] * TPN + cq];
        #pragma unroll
        for (int q = 0; q < 8; q++) acc8(a, v[q]);
    }
    ((uint4*)out)[(size_t)node * TPN + cq] = pack8(a, dinv[node]);
}

// ---------------------------------------------------------------------------
// MFMA bf16 GEMM (K=64, N=128): hs2 = f2bf(dinv*selu(a1 @ W1 + b)).
// 256 blocks x 128 rows; compute-dense so low grid is fine.
// ---------------------------------------------------------------------------
__global__ __launch_bounds__(256) void gemm1_kernel(
    const unsigned short* __restrict__ A, const unsigned short* __restrict__ Wp,
    const float* __restrict__ bias, const float* __restrict__ dinv,
    unsigned short* __restrict__ hs2) {
    constexpr int LDA = 72;  // 64 + 8 bf16 pad
    __shared__ unsigned short As[128 * LDA];
    int t = threadIdx.x;
    int R0 = blockIdx.x * 128;

    // stage A tile (128 rows x 64 bf16 = 8 uint4 chunks/row)
    for (int c = t; c < 128 * 8; c += 256) {
        int row = c >> 3, off = c & 7;
        *(uint4*)&As[row * LDA + off * 8] =
            *(const uint4*)&A[(size_t)(R0 + row) * 64 + off * 8];
    }
    __syncthreads();

    int wave = t >> 6, l = t & 63;
    int ml = l & 15, q = l >> 4;
    int wr = wave * 32;
    f32x4 acc[2][8];
    #pragma unroll
    for (int mf = 0; mf < 2; mf++)
        #pragma unroll
        for (int nf = 0; nf < 8; nf++) acc[mf][nf] = (f32x4){0.f, 0.f, 0.f, 0.f};
    const bf16x8* wp8 = (const bf16x8*)Wp;
    #pragma unroll
    for (int ks = 0; ks < 2; ks++) {
        bf16x8 af[2];
        #pragma unroll
        for (int mf = 0; mf < 2; mf++)
            af[mf] = *(const bf16x8*)&As[(wr + mf * 16 + ml) * LDA + ks * 32 + q * 8];
        bf16x8 bfr[8];
        #pragma unroll
        for (int nf = 0; nf < 8; nf++)
            bfr[nf] = wp8[(size_t)(nf * 2 + ks) * 64 + l];
        #pragma unroll
        for (int mf = 0; mf < 2; mf++)
            #pragma unroll
            for (int nf = 0; nf < 8; nf++)
                acc[mf][nf] = __builtin_amdgcn_mfma_f32_16x16x32_bf16(
                    af[mf], bfr[nf], acc[mf][nf], 0, 0, 0);
    }
    float bj[8];
    #pragma unroll
    for (int nf = 0; nf < 8; nf++) bj[nf] = bias[nf * 16 + ml];
    #pragma unroll
    for (int mf = 0; mf < 2; mf++) {
        #pragma unroll
        for (int r = 0; r < 4; r++) {
            int row = R0 + wr + mf * 16 + q * 4 + r;
            float dv = dinv[row];
            #pragma unroll
            for (int nf = 0; nf < 8; nf++) {
                float v = dv * selu_f(acc[mf][nf][r] + bj[nf]);
                hs2[(size_t)row * 128 + nf * 16 + ml] = f2bf(v);
            }
        }
    }
}

// ---------------------------------------------------------------------------
// MFMA bf16 GEMM (K=128): selu + column max -> atomicMax into m_enc (exact).
// ---------------------------------------------------------------------------
__global__ __launch_bounds__(256) void gemm2_kernel(
    const unsigned short* __restrict__ A, const unsigned short* __restrict__ Wp,
    const float* __restrict__ bias, unsigned int* __restrict__ menc, int Nfull) {
    constexpr int KS = 4;
    constexpr int LDA = 136;  // 128 + 8
    constexpr int CPR = 16;
    __shared__ unsigned short As[128 * LDA];
    int t = threadIdx.x;
    int wave = t >> 6, l = t & 63;
    int ml = l & 15, q = l >> 4;
    int R0 = blockIdx.x * 128;
    int cb = blockIdx.y * 128;

    for (int c = t; c < 128 * CPR; c += 256) {
        int row = c / CPR, off = c % CPR;
        *(uint4*)&As[row * LDA + off * 8] =
            *(const uint4*)&A[(size_t)(R0 + row) * 128 + off * 8];
    }
    __syncthreads();

    f32x4 acc[2][8];
    #pragma unroll
    for (int mf = 0; mf < 2; mf++)
        #pragma unroll
        for (int nf = 0; nf < 8; nf++) acc[mf][nf] = (f32x4){0.f, 0.f, 0.f, 0.f};

    const bf16x8* wp8 = (const bf16x8*)Wp;
    int wr = wave * 32;
    #pragma unroll
    for (int ks = 0; ks < KS; ks++) {
        bf16x8 af[2];
        #pragma unroll
        for (int mf = 0; mf < 2; mf++)
            af[mf] = *(const bf16x8*)&As[(wr + mf * 16 + ml) * LDA + ks * 32 + q * 8];
        bf16x8 bfr[8];
        #pragma unroll
        for (int nf = 0; nf < 8; nf++)
            bfr[nf] = wp8[(size_t)(((cb >> 4) + nf) * KS + ks) * 64 + l];
        #pragma unroll
        for (int mf = 0; mf < 2; mf++)
            #pragma unroll
            for (int nf = 0; nf < 8; nf++)
                acc[mf][nf] = __builtin_amdgcn_mfma_f32_16x16x32_bf16(
                    af[mf], bfr[nf], acc[mf][nf], 0, 0, 0);
    }

    // selu + column max; C/D layout: col = ml, row = q*4 + r
    float cmax[8];
    #pragma unroll
    for (int nf = 0; nf < 8; nf++) {
        float bj = bias[cb + nf * 16 + ml];
        float v = -INFINITY;
        #pragma unroll
        for (int mf = 0; mf < 2; mf++)
            #pragma unroll
            for (int r = 0; r < 4; r++)
                v = fmaxf(v, selu_f(acc[mf][nf][r] + bj));
        v = fmaxf(v, __shfl_xor(v, 16, 64));
        v = fmaxf(v, __shfl_xor(v, 32, 64));
        cmax[nf] = v;
    }
    __syncthreads();  // before reusing As as f32 scratch
    float* redf = (float*)As;  // [4 waves][128 cols]
    if (ml == l) {  // lanes 0..15
        #pragma unroll
        for (int nf = 0; nf < 8; nf++) redf[wave * 128 + nf * 16 + l] = cmax[nf];
    }
    __syncthreads();
    if (t < 128) {
        float v = redf[t];
        v = fmaxf(v, redf[128 + t]);
        v = fmaxf(v, redf[256 + t]);
        v = fmaxf(v, redf[384 + t]);
        int b = blockIdx.x >> 5;  // 32 row-tiles per batch
        atomicMax(&menc[b * 512 + cb + t], fenc(v));
    }
}

// ---------------------------------------------------------------------------
// lat: grid (8 batches, 16 col-groups of 32).  lat[b][c] =
// selu(sum_k m[b][k]*w_e2[k][c] + b_e2[c]).  k split 8 ways, LDS reduce.
// ---------------------------------------------------------------------------
__global__ __launch_bounds__(256) void lat_kernel(
    const unsigned int* __restrict__ menc, const float* __restrict__ w_e2,
    const float* __restrict__ b_e2, float* __restrict__ lat) {
    int b = blockIdx.x;
    int cg = blockIdx.y;
    int t = threadIdx.x;
    __shared__ float ml[512];
    __shared__ float red[8][32];
    ml[t] = fdec(menc[b * 512 + t]);
    ml[t + 256] = fdec(menc[b * 512 + t + 256]);
    __syncthreads();
    int cl = t & 31;          // column within group
    int kg = t >> 5;          // 0..7, k-chunks of 64
    int c = cg * 32 + cl;
    const float* wp = w_e2 + (size_t)(kg * 64) * 512 + c;
    const float* mlp = ml + kg * 64;
    float acc = 0.f;
    #pragma unroll 16
    for (int k = 0; k < 64; k++) acc = fmaf(mlp[k], wp[(size_t)k * 512], acc);
    red[kg][cl] = acc;
    __syncthreads();
    if (t < 32) {
        float v = ((red[0][t] + red[1][t]) + (red[2][t] + red[3][t])) +
                  ((red[4][t] + red[5][t]) + (red[6][t] + red[7][t]));
        lat[b * 512 + cg * 32 + t] = selu_f(v + b_e2[cg * 32 + t]);
    }
}

// ---------------------------------------------------------------------------
// latw + decode: 64 blocks = 8 batches x 8 point-slices.  Each block
// recomputes the tiny latw reduction (512x6) then decodes its 512 points.
// ---------------------------------------------------------------------------
__global__ __launch_bounds__(256) void latw_decode_kernel(
    const float* __restrict__ lat, const float* __restrict__ w_d1,
    const float* __restrict__ b_d1, const float* __restrict__ w_d2,
    const float* __restrict__ b_d2, float* __restrict__ out) {
    int b = blockIdx.x >> 3;   // batch
    int sl = blockIdx.x & 7;   // point slice
    int t = threadIdx.x;
    __shared__ float ll[512];
    __shared__ float red[6][256];
    __shared__ float lw[6];
    ll[t] = lat[b * 512 + t];
    ll[t + 256] = lat[b * 512 + t + 256];
    __syncthreads();
    float p[6] = {0.f, 0.f, 0.f, 0.f, 0.f, 0.f};
    for (int k = t; k < 512; k += 256) {
        float lv = ll[k];
        #pragma unroll
        for (int j = 0; j < 3; j++) {
            p[j]     = fmaf(lv, w_d1[k * 3 + j], p[j]);
            p[3 + j] = fmaf(lv, w_d2[k * 3 + j], p[3 + j]);
        }
    }
    #pragma unroll
    for (int j = 0; j < 6; j++) red[j][t] = p[j];
    __syncthreads();
    for (int s = 128; s > 0; s >>= 1) {
        if (t < s) {
            #pragma unroll
            for (int j = 0; j < 6; j++) red[j][t] += red[j][t + s];
        }
        __syncthreads();
    }
    if (t < 3) {
        lw[t]     = red[t][0] + b_d1[t];
        lw[3 + t] = red[3 + t][0] + b_d2[t];
    }
    __syncthreads();
    float l10 = lw[0], l11 = lw[1], l12 = lw[2];
    float l20 = lw[3], l21 = lw[4], l22 = lw[5];
    float w1a0 = w_d1[1536 + 0], w1a1 = w_d1[1536 + 1], w1a2 = w_d1[1536 + 2];
    float w1b0 = w_d1[1539 + 0], w1b1 = w_d1[1539 + 1], w1b2 = w_d1[1539 + 2];
    float w2a0 = w_d2[1536 + 0], w2a1 = w_d2[1536 + 1], w2a2 = w_d2[1536 + 2];
    float w2b0 = w_d2[1539 + 0], w2b1 = w_d2[1539 + 1], w2b2 = w_d2[1539 + 2];
    float w2c0 = w_d2[1542 + 0], w2c1 = w_d2[1542 + 1], w2c2 = w_d2[1542 + 2];
    {
        int n = sl * 512 + t;
        #pragma unroll
        for (int half = 0; half < 2; half++) {
            int i = n / 46;
            int j = n - i * 46;
            float y0 = fmaf((float)i, 119.f / 90.f, 1.f);
            float y1 = fmaf((float)j, 59.f / 45.f, 1.f);
            float k0 = selu_f(l10 + y0 * w1a0 + y1 * w1b0);
            float k1 = selu_f(l11 + y0 * w1a1 + y1 * w1b1);
            float k2 = selu_f(l12 + y0 * w1a2 + y1 * w1b2);
            float o0 = selu_f(l20 + k0 * w2a0 + k1 * w2b0 + k2 * w2c0);
            float o1 = selu_f(l21 + k0 * w2a1 + k1 * w2b1 + k2 * w2c1);
            float o2 = selu_f(l22 + k0 * w2a2 + k1 * w2b2 + k2 * w2c2);
            size_t pidx = (size_t)(b * 4096 + n) * 3;
            out[pidx + 0] = o0;
            out[pidx + 1] = o1;
            out[pidx + 2] = o2;
            n += 256;
        }
    }
}

// ---------------------------------------------------------------------------
extern "C" void kernel_launch(void* const* d_in, const int* in_sizes, int n_in,
                              void* d_out, int out_size, void* d_ws, size_t ws_size,
                              hipStream_t stream) {
    const float* x    = (const float*)d_in[0];
    const int*   knn  = (const int*)d_in[1];
    const float* w_e1 = (const float*)d_in[2];
    const float* b_e1 = (const float*)d_in[3];
    const float* w_g1 = (const float*)d_in[4];
    const float* b_g1 = (const float*)d_in[5];
    const float* w_g2 = (const float*)d_in[6];
    const float* b_g2 = (const float*)d_in[7];
    const float* w_e2 = (const float*)d_in[8];
    const float* b_e2 = (const float*)d_in[9];
    const float* w_d1 = (const float*)d_in[10];
    const float* b_d1 = (const float*)d_in[11];
    const float* w_d2 = (const float*)d_in[12];
    const float* b_d2 = (const float*)d_in[13];
    float* out = (float*)d_out;

    const int BN = in_sizes[0] / 3;   // 32768
    const int E  = in_sizes[1] / 2;   // 524288
    const int Bb = BN / 4096;         // 8
    const int* src = knn;
    const int* dst = knn + E;

    size_t off = 0;
    auto alloc = [&](size_t bytes) -> void* {
        void* p = (char*)d_ws + off;
        off += (bytes + 255) & ~(size_t)255;
        return p;
    };
    unsigned short* hs1 = (unsigned short*)alloc((size_t)(BN + 1) * 64 * 2);
    unsigned short* hs2 = (unsigned short*)alloc((size_t)(BN + 1) * 128 * 2);
    unsigned short* a1  = (unsigned short*)alloc((size_t)BN * 64 * 2);
    unsigned short* a2  = (unsigned short*)alloc((size_t)BN * 128 * 2);
    unsigned short* Wp1 = (unsigned short*)alloc((size_t)16 * 64 * 8 * 2);
    unsigned short* Wp2 = (unsigned short*)alloc((size_t)128 * 64 * 8 * 2);
    unsigned int* menc = (unsigned int*)alloc((size_t)Bb * 512 * 4);
    float* lat    = (float*)alloc((size_t)Bb * 512 * 4);
    float* dinv   = (float*)alloc((size_t)BN * 4);
    int*   cnt    = (int*)alloc((size_t)BN * 4);
    int*   epos   = (int*)alloc((size_t)E * 4);
    int*   indptr = (int*)alloc((size_t)(BN + 1) * 4);
    int*   bsums  = (int*)alloc((size_t)128 * 4);
    int*   ssrc   = (int*)alloc((size_t)(E + 7 * BN + 1024) * 4);
    (void)ws_size;

    const int nb_scatter = (E + 255) / 256;  // 2048

    // prep: zero cnt + sentinel rows + m_enc, pack both weight matrices
    prep_kernel<<<273, 256, 0, stream>>>(
        cnt, (unsigned int*)(hs1 + (size_t)BN * 64),
        (unsigned int*)(hs2 + (size_t)BN * 128), menc, w_g1, Wp1, w_g2, Wp2);
    // count + per-edge slot
    count_kernel<<<(E + 255) / 256, 256, 0, stream>>>(dst, cnt, epos, E);
    scanA_kernel<<<BN / 256, 256, 0, stream>>>(cnt, bsums, dinv);
    scanC_kernel<<<BN / 256, 256, 0, stream>>>(cnt, bsums, indptr, ssrc, BN);
    // scatter || encoder
    scatter_cov_kernel<<<nb_scatter + 128, 256, 0, stream>>>(
        src, dst, epos, indptr, ssrc, E, nb_scatter,
        x, w_e1, b_e1, dinv, hs1);

    // GCN1 split: agg(64, 1024 blocks) -> MFMA K=64 -> bf16 hs2 (prescaled)
    agg_kernel<64><<<BN / 32, 256, 0, stream>>>(hs1, dinv, indptr, ssrc, a1, BN);
    gemm1_kernel<<<BN / 128, 256, 0, stream>>>(a1, Wp1, b_g1, dinv, hs2);

    // GCN2 split: agg(128, 2048 blocks) -> MFMA + column max (atomicMax)
    agg_kernel<128><<<BN / 16, 256, 0, stream>>>(hs2, dinv, indptr, ssrc, a2, BN);
    gemm2_kernel<<<dim3(BN / 128, 4), 256, 0, stream>>>(a2, Wp2, b_g2, menc, 512);

    // latent matmul, parallel over 8x16 blocks
    lat_kernel<<<dim3(Bb, 16), 256, 0, stream>>>(menc, w_e2, b_e2, lat);

    // latw + decode (64 blocks: 8 batches x 8 slices)
    latw_decode_kernel<<<Bb * 8, 256, 0, stream>>>(lat, w_d1, b_d1, w_d2, b_d2, out);
}

// Round 13
// 205.034 us; speedup vs baseline: 1.2221x; 1.0046x over previous
//
#include <hip/hip_runtime.h>
#include <math.h>

#define SELU_SCALE 1.0507009873554804934193349852946f
#define SELU_ALPHA 1.6732632423543772848170429916717f

typedef short bf16x8 __attribute__((ext_vector_type(8)));
typedef float f32x4 __attribute__((ext_vector_type(4)));

__device__ __forceinline__ float selu_f(float x) {
    return SELU_SCALE * (x > 0.f ? x : SELU_ALPHA * expm1f(x));
}

__device__ __forceinline__ unsigned short f2bf(float f) {
    unsigned int u = __float_as_uint(f);
    u += 0x7FFF + ((u >> 16) & 1);  // round-to-nearest-even
    return (unsigned short)(u >> 16);
}
__device__ __forceinline__ float bflo(unsigned int u) { return __uint_as_float(u << 16); }
__device__ __forceinline__ float bfhi(unsigned int u) { return __uint_as_float(u & 0xFFFF0000u); }

// monotonic float<->uint encoding (order-preserving); max in uint == max in float
__device__ __forceinline__ unsigned int fenc(float f) {
    unsigned int u = __float_as_uint(f);
    return (u & 0x80000000u) ? ~u : (u | 0x80000000u);
}
__device__ __forceinline__ float fdec(unsigned int u) {
    return __uint_as_float((u & 0x80000000u) ? (u ^ 0x80000000u) : ~u);
}

__device__ __forceinline__ void acc8(float* a, uint4 v) {
    a[0] += bflo(v.x); a[1] += bfhi(v.x);
    a[2] += bflo(v.y); a[3] += bfhi(v.y);
    a[4] += bflo(v.z); a[5] += bfhi(v.z);
    a[6] += bflo(v.w); a[7] += bfhi(v.w);
}

__device__ __forceinline__ uint4 pack8(const float* a, float dv) {
    uint4 pk;
    pk.x = (unsigned int)f2bf(a[0] * dv) | ((unsigned int)f2bf(a[1] * dv) << 16);
    pk.y = (unsigned int)f2bf(a[2] * dv) | ((unsigned int)f2bf(a[3] * dv) << 16);
    pk.z = (unsigned int)f2bf(a[4] * dv) | ((unsigned int)f2bf(a[5] * dv) << 16);
    pk.w = (unsigned int)f2bf(a[6] * dv) | ((unsigned int)f2bf(a[7] * dv) << 16);
    return pk;
}

// ---------------------------------------------------------------------------
// prep: blocks 0..127 zero cnt; block 128 zeros sentinel rows + m_enc;
// blocks 129..272 pack weights into MFMA B-fragment layout.
// ---------------------------------------------------------------------------
__global__ __launch_bounds__(256) void prep_kernel(
    int* __restrict__ cnt, unsigned int* __restrict__ pad1,
    unsigned int* __restrict__ pad2, unsigned int* __restrict__ menc,
    const float* __restrict__ W1, unsigned short* __restrict__ Wp1,
    const float* __restrict__ W2, unsigned short* __restrict__ Wp2) {
    int b = blockIdx.x;
    int t = threadIdx.x;
    if (b < 128) {
        cnt[b * 256 + t] = 0;
    } else if (b == 128) {
        if (t < 32) pad1[t] = 0;   // hs1 sentinel row (64 bf16)
        if (t < 64) pad2[t] = 0;   // hs2 sentinel row (128 bf16)
        for (int i = t; i < 4096; i += 256) menc[i] = 0u;  // enc-min
    } else {
        if (t >= 64) return;
        int fb = b - 129;
        const float* W; unsigned short* Wp; int K, N, f;
        if (fb < 16) { W = W1; Wp = Wp1; K = 64; N = 128; f = fb; }
        else         { W = W2; Wp = Wp2; K = 128; N = 512; f = fb - 16; }
        int l = t;  // 0..63
        int KS = K / 32;
        int nt = f / KS, ks = f % KS;
        int ncol = nt * 16 + (l & 15);
        int k0 = ks * 32 + (l >> 4) * 8;
        unsigned short v[8];
        #pragma unroll
        for (int j = 0; j < 8; j++) v[j] = f2bf(W[(size_t)(k0 + j) * N + ncol]);
        *(uint4*)&Wp[((size_t)f * 64 + l) * 8] = *(uint4*)v;
    }
}

// count degrees AND record each edge's slot within its destination's segment
__global__ void count_kernel(const int* __restrict__ dst, int* __restrict__ cnt,
                             int* __restrict__ epos, int E) {
    int e = blockIdx.x * blockDim.x + threadIdx.x;
    if (e < E) epos[e] = atomicAdd(&cnt[dst[e]], 1);
}

// --- parallel exclusive scan over padded counts ((c+7)&~7) ---
__global__ __launch_bounds__(256) void scanA_kernel(const int* __restrict__ cnt,
                                                    int* __restrict__ blockSums,
                                                    float* __restrict__ dinv) {
    __shared__ int red[256];
    int t = threadIdx.x;
    int i = blockIdx.x * 256 + t;
    int c = cnt[i];
    dinv[i] = rsqrtf((float)(c + 1));
    red[t] = (c + 7) & ~7;
    __syncthreads();
    for (int s = 128; s > 0; s >>= 1) {
        if (t < s) red[t] += red[t + s];
        __syncthreads();
    }
    if (t == 0) blockSums[blockIdx.x] = red[0];
}

__global__ __launch_bounds__(256) void scanC_kernel(
    const int* __restrict__ cnt, const int* __restrict__ bsums,
    int* __restrict__ indptr, int* __restrict__ ssrc, int n) {
    __shared__ int sc[256];
    __shared__ int bs[128];
    int t = threadIdx.x;
    int ownSum = bsums[blockIdx.x];
    if (t < 128) bs[t] = bsums[t];
    int i = blockIdx.x * 256 + t;
    int c = cnt[i];
    int pc = (c + 7) & ~7;
    sc[t] = pc;
    __syncthreads();
    for (int off = 1; off < 128; off <<= 1) {
        int v = (t >= off && t < 128) ? bs[t - off] : 0;
        __syncthreads();
        if (t < 128) bs[t] += v;
        __syncthreads();
    }
    for (int off = 1; off < 256; off <<= 1) {
        int v = t >= off ? sc[t - off] : 0;
        __syncthreads();
        sc[t] += v;
        __syncthreads();
    }
    int blockOff = bs[blockIdx.x] - ownSum;  // exclusive block offset
    int ip = blockOff + sc[t] - pc;          // exclusive elem offset
    indptr[i] = ip;
    for (int k = c; k < pc; k++) ssrc[ip + k] = n;  // sentinel zero-row
    if (i == n - 1) indptr[n] = blockOff + sc[t];
}

// ---------------------------------------------------------------------------
// scatter (blocks 0..nb_scatter-1) || cov_enc (remaining 128 blocks).
// ---------------------------------------------------------------------------
__global__ __launch_bounds__(256) void scatter_cov_kernel(
    const int* __restrict__ src, const int* __restrict__ dst,
    const int* __restrict__ epos, const int* __restrict__ indptr,
    int* __restrict__ ssrc, int E, int nb_scatter,
    const float* __restrict__ x, const float* __restrict__ w_e1,
    const float* __restrict__ b_e1, const float* __restrict__ dinv,
    unsigned short* __restrict__ hs1) {
    int t = threadIdx.x;
    if ((int)blockIdx.x < nb_scatter) {
        int e = blockIdx.x * 256 + t;
        if (e < E) ssrc[indptr[dst[e]] + epos[e]] = src[e];
        return;
    }
    // ---- cov_enc part ----
    __shared__ float Wl[12 * 64];
    __shared__ float Bl[64];
    __shared__ float xs[280 * 3];
    int cb = blockIdx.x - nb_scatter;  // 0..127
    for (int i = t; i < 768; i += 256) Wl[i] = w_e1[i];
    if (t < 64) Bl[t] = b_e1[t];
    int p0 = cb * 256;
    int n0 = p0 & 4095;
    const float* xb = x + (size_t)(p0 - n0) * 3;  // batch base (256 | 4096)
    for (int idx = t; idx < 840; idx += 256) {
        int slot = idx / 3, d = idx - slot * 3;
        int g = n0 - 12 + slot;
        g = g < 0 ? 0 : (g > 4095 ? 4095 : g);
        xs[idx] = xb[g * 3 + d];
    }
    __syncthreads();
    int p = p0 + t;
    int n = n0 + t;
    int lo = n - 12 < 0 ? 0 : n - 12;
    int hi = n + 12 > 4095 ? 4095 : n + 12;
    int slo = lo - n0 + 12, shi = hi - n0 + 12;
    float sx = 0.f, sy = 0.f, sz = 0.f;
    float sxx = 0.f, sxy = 0.f, sxz = 0.f, syy = 0.f, syz = 0.f, szz = 0.f;
    for (int s = slo; s <= shi; s++) {
        float xv = xs[s * 3 + 0], yv = xs[s * 3 + 1], zv = xs[s * 3 + 2];
        sx += xv; sy += yv; sz += zv;
        sxx = fmaf(xv, xv, sxx); sxy = fmaf(xv, yv, sxy); sxz = fmaf(xv, zv, sxz);
        syy = fmaf(yv, yv, syy); syz = fmaf(yv, zv, syz); szz = fmaf(zv, zv, szz);
    }
    float cntf = (float)(shi - slo + 1);
    float rin = 1.f / cntf;
    float mx = sx * rin, my = sy * rin, mz = sz * rin;
    const float inv23 = 1.f / 23.f;
    float c00 = (sxx - sx * mx) * inv23;
    float c01 = (sxy - sx * my) * inv23;
    float c02 = (sxz - sx * mz) * inv23;
    float c11 = (syy - sy * my) * inv23;
    float c12 = (syz - sy * mz) * inv23;
    float c22 = (szz - sz * mz) * inv23;
    float feat[12];
    feat[0] = xs[(t + 12) * 3 + 0];
    feat[1] = xs[(t + 12) * 3 + 1];
    feat[2] = xs[(t + 12) * 3 + 2];
    feat[3] = c00; feat[4] = c01; feat[5]  = c02;
    feat[6] = c01; feat[7] = c11; feat[8]  = c12;
    feat[9] = c02; feat[10] = c12; feat[11] = c22;
    float dv = dinv[p];
    unsigned int* hp = (unsigned int*)(hs1 + (size_t)p * 64);
    for (int c = 0; c < 64; c += 2) {
        float a0 = Bl[c], a1 = Bl[c + 1];
        #pragma unroll
        for (int i = 0; i < 12; i++) {
            a0 = fmaf(feat[i], Wl[i * 64 + c], a0);
            a1 = fmaf(feat[i], Wl[i * 64 + c + 1], a1);
        }
        unsigned int pk = (unsigned int)f2bf(dv * selu_f(a0)) |
                          ((unsigned int)f2bf(dv * selu_f(a1)) << 16);
        hp[c >> 1] = pk;
    }
}

// ---------------------------------------------------------------------------
// Aggregation, standalone for max occupancy.  8 channels (uint4) per thread,
// 8-deep gather batching, int4-vectorized index loads (rows 8-aligned).
// ROWSTRIDE = uint4 chunks per row of the table; CQ0 = chunk offset.
// agg64: ROWSTRIDE=8, CQ0=0 (whole row).  agg128 runs as TWO passes
// (CQ0=0 then CQ0=8): each pass touches one 128B line/row -> 4.2 MB
// working set, fits per-XCD L2.
// ---------------------------------------------------------------------------
template <int ROWSTRIDE, int CQ0>
__global__ __launch_bounds__(256) void agg_kernel(
    const unsigned short* __restrict__ hs, const float* __restrict__ dinv,
    const int* __restrict__ indptr, const int* __restrict__ ssrc,
    unsigned short* __restrict__ out, int n_nodes) {
    constexpr int TPN = 8;  // 8 uint4-chunks per node per pass
    int node = blockIdx.x * (256 / TPN) + threadIdx.x / TPN;
    int cq = CQ0 + (threadIdx.x % TPN);
    if (node >= n_nodes) return;
    const uint4* hp = (const uint4*)hs;
    float a[8];
    {
        uint4 u = hp[(size_t)node * ROWSTRIDE + cq];
        a[0] = bflo(u.x); a[1] = bfhi(u.x);
        a[2] = bflo(u.y); a[3] = bfhi(u.y);
        a[4] = bflo(u.z); a[5] = bfhi(u.z);
        a[6] = bflo(u.w); a[7] = bfhi(u.w);
    }
    int beg = indptr[node], end = indptr[node + 1];
    for (int j = beg; j < end; j += 8) {
        int4 sa = *(const int4*)&ssrc[j];
        int4 sb = *(const int4*)&ssrc[j + 4];
        uint4 v0 = hp[(size_t)sa.x * ROWSTRIDE + cq];
        uint4 v1 = hp[(size_t)sa.y * ROWSTRIDE + cq];
        uint4 v2 = hp[(size_t)sa.z * ROWSTRIDE + cq];
        uint4 v3 = hp[(size_t)sa.w * ROWSTRIDE + cq];
        uint4 v4 = hp[(size_t)sb.x * ROWSTRIDE + cq];
        uint4 v5 = hp[(size_t)sb.y * ROWSTRIDE + cq];
        uint4 v6 = hp[(size_t)sb.z * ROWSTRIDE + cq];
        uint4 v7 = hp[(size_t)sb.w * ROWSTRIDE + cq];
        acc8(a, v0); acc8(a, v1); acc8(a, v2); acc8(a, v3);
        acc8(a, v4); acc8(a, v5); acc8(a, v6); acc8(a, v7);
    }
    ((uint4*)out)[(size_t)node * ROWSTRIDE + cq] = pack8(a, dinv[node]);
}

// ---------------------------------------------------------------------------
// MFMA bf16 GEMM (K=64, N=128): hs2 = f2bf(dinv*selu(a1 @ W1 + b)).
// ---------------------------------------------------------------------------
__global__ __launch_bounds__(256) void gemm1_kernel(
    const unsigned short* __restrict__ A, const unsigned short* __restrict__ Wp,
    const float* __restrict__ bias, const float* __restrict__ dinv,
    unsigned short* __restrict__ hs2) {
    constexpr int LDA = 72;  // 64 + 8 bf16 pad
    __shared__ unsigned short As[128 * LDA];
    int t = threadIdx.x;
    int R0 = blockIdx.x * 128;

    for (int c = t; c < 128 * 8; c += 256) {
        int row = c >> 3, off = c & 7;
        *(uint4*)&As[row * LDA + off * 8] =
            *(const uint4*)&A[(size_t)(R0 + row) * 64 + off * 8];
    }
    __syncthreads();

    int wave = t >> 6, l = t & 63;
    int ml = l & 15, q = l >> 4;
    int wr = wave * 32;
    f32x4 acc[2][8];
    #pragma unroll
    for (int mf = 0; mf < 2; mf++)
        #pragma unroll
        for (int nf = 0; nf < 8; nf++) acc[mf][nf] = (f32x4){0.f, 0.f, 0.f, 0.f};
    const bf16x8* wp8 = (const bf16x8*)Wp;
    #pragma unroll
    for (int ks = 0; ks < 2; ks++) {
        bf16x8 af[2];
        #pragma unroll
        for (int mf = 0; mf < 2; mf++)
            af[mf] = *(const bf16x8*)&As[(wr + mf * 16 + ml) * LDA + ks * 32 + q * 8];
        bf16x8 bfr[8];
        #pragma unroll
        for (int nf = 0; nf < 8; nf++)
            bfr[nf] = wp8[(size_t)(nf * 2 + ks) * 64 + l];
        #pragma unroll
        for (int mf = 0; mf < 2; mf++)
            #pragma unroll
            for (int nf = 0; nf < 8; nf++)
                acc[mf][nf] = __builtin_amdgcn_mfma_f32_16x16x32_bf16(
                    af[mf], bfr[nf], acc[mf][nf], 0, 0, 0);
    }
    float bj[8];
    #pragma unroll
    for (int nf = 0; nf < 8; nf++) bj[nf] = bias[nf * 16 + ml];
    #pragma unroll
    for (int mf = 0; mf < 2; mf++) {
        #pragma unroll
        for (int r = 0; r < 4; r++) {
            int row = R0 + wr + mf * 16 + q * 4 + r;
            float dv = dinv[row];
            #pragma unroll
            for (int nf = 0; nf < 8; nf++) {
                float v = dv * selu_f(acc[mf][nf][r] + bj[nf]);
                hs2[(size_t)row * 128 + nf * 16 + ml] = f2bf(v);
            }
        }
    }
}

// ---------------------------------------------------------------------------
// MFMA bf16 GEMM (K=128): selu + column max -> atomicMax into m_enc (exact).
// ---------------------------------------------------------------------------
__global__ __launch_bounds__(256) void gemm2_kernel(
    const unsigned short* __restrict__ A, const unsigned short* __restrict__ Wp,
    const float* __restrict__ bias, unsigned int* __restrict__ menc, int Nfull) {
    constexpr int KS = 4;
    constexpr int LDA = 136;  // 128 + 8
    constexpr int CPR = 16;
    __shared__ unsigned short As[128 * LDA];
    int t = threadIdx.x;
    int wave = t >> 6, l = t & 63;
    int ml = l & 15, q = l >> 4;
    int R0 = blockIdx.x * 128;
    int cb = blockIdx.y * 128;

    for (int c = t; c < 128 * CPR; c += 256) {
        int row = c / CPR, off = c % CPR;
        *(uint4*)&As[row * LDA + off * 8] =
            *(const uint4*)&A[(size_t)(R0 + row) * 128 + off * 8];
    }
    __syncthreads();

    f32x4 acc[2][8];
    #pragma unroll
    for (int mf = 0; mf < 2; mf++)
        #pragma unroll
        for (int nf = 0; nf < 8; nf++) acc[mf][nf] = (f32x4){0.f, 0.f, 0.f, 0.f};

    const bf16x8* wp8 = (const bf16x8*)Wp;
    int wr = wave * 32;
    #pragma unroll
    for (int ks = 0; ks < KS; ks++) {
        bf16x8 af[2];
        #pragma unroll
        for (int mf = 0; mf < 2; mf++)
            af[mf] = *(const bf16x8*)&As[(wr + mf * 16 + ml) * LDA + ks * 32 + q * 8];
        bf16x8 bfr[8];
        #pragma unroll
        for (int nf = 0; nf < 8; nf++)
            bfr[nf] = wp8[(size_t)(((cb >> 4) + nf) * KS + ks) * 64 + l];
        #pragma unroll
        for (int mf = 0; mf < 2; mf++)
            #pragma unroll
            for (int nf = 0; nf < 8; nf++)
                acc[mf][nf] = __builtin_amdgcn_mfma_f32_16x16x32_bf16(
                    af[mf], bfr[nf], acc[mf][nf], 0, 0, 0);
    }

    // selu + column max; C/D layout: col = ml, row = q*4 + r
    float cmax[8];
    #pragma unroll
    for (int nf = 0; nf < 8; nf++) {
        float bj = bias[cb + nf * 16 + ml];
        float v = -INFINITY;
        #pragma unroll
        for (int mf = 0; mf < 2; mf++)
            #pragma unroll
            for (int r = 0; r < 4; r++)
                v = fmaxf(v, selu_f(acc[mf][nf][r] + bj));
        v = fmaxf(v, __shfl_xor(v, 16, 64));
        v = fmaxf(v, __shfl_xor(v, 32, 64));
        cmax[nf] = v;
    }
    __syncthreads();  // before reusing As as f32 scratch
    float* redf = (float*)As;  // [4 waves][128 cols]
    if (ml == l) {  // lanes 0..15
        #pragma unroll
        for (int nf = 0; nf < 8; nf++) redf[wave * 128 + nf * 16 + l] = cmax[nf];
    }
    __syncthreads();
    if (t < 128) {
        float v = redf[t];
        v = fmaxf(v, redf[128 + t]);
        v = fmaxf(v, redf[256 + t]);
        v = fmaxf(v, redf[384 + t]);
        int b = blockIdx.x >> 5;  // 32 row-tiles per batch
        atomicMax(&menc[b * 512 + cb + t], fenc(v));
    }
}

// ---------------------------------------------------------------------------
// lat: grid (8 batches, 16 col-groups of 32).  lat[b][c] =
// selu(sum_k m[b][k]*w_e2[k][c] + b_e2[c]).  k split 8 ways, LDS reduce.
// ---------------------------------------------------------------------------
__global__ __launch_bounds__(256) void lat_kernel(
    const unsigned int* __restrict__ menc, const float* __restrict__ w_e2,
    const float* __restrict__ b_e2, float* __restrict__ lat) {
    int b = blockIdx.x;
    int cg = blockIdx.y;
    int t = threadIdx.x;
    __shared__ float ml[512];
    __shared__ float red[8][32];
    ml[t] = fdec(menc[b * 512 + t]);
    ml[t + 256] = fdec(menc[b * 512 + t + 256]);
    __syncthreads();
    int cl = t & 31;          // column within group
    int kg = t >> 5;          // 0..7, k-chunks of 64
    int c = cg * 32 + cl;
    const float* wp = w_e2 + (size_t)(kg * 64) * 512 + c;
    const float* mlp = ml + kg * 64;
    float acc = 0.f;
    #pragma unroll 16
    for (int k = 0; k < 64; k++) acc = fmaf(mlp[k], wp[(size_t)k * 512], acc);
    red[kg][cl] = acc;
    __syncthreads();
    if (t < 32) {
        float v = ((red[0][t] + red[1][t]) + (red[2][t] + red[3][t])) +
                  ((red[4][t] + red[5][t]) + (red[6][t] + red[7][t]));
        lat[b * 512 + cg * 32 + t] = selu_f(v + b_e2[cg * 32 + t]);
    }
}

// ---------------------------------------------------------------------------
// latw + decode: 64 blocks = 8 batches x 8 point-slices.  Each block
// recomputes the tiny latw reduction (512x6) then decodes its 512 points.
// ---------------------------------------------------------------------------
__global__ __launch_bounds__(256) void latw_decode_kernel(
    const float* __restrict__ lat, const float* __restrict__ w_d1,
    const float* __restrict__ b_d1, const float* __restrict__ w_d2,
    const float* __restrict__ b_d2, float* __restrict__ out) {
    int b = blockIdx.x >> 3;   // batch
    int sl = blockIdx.x & 7;   // point slice
    int t = threadIdx.x;
    __shared__ float ll[512];
    __shared__ float red[6][256];
    __shared__ float lw[6];
    ll[t] = lat[b * 512 + t];
    ll[t + 256] = lat[b * 512 + t + 256];
    __syncthreads();
    float p[6] = {0.f, 0.f, 0.f, 0.f, 0.f, 0.f};
    for (int k = t; k < 512; k += 256) {
        float lv = ll[k];
        #pragma unroll
        for (int j = 0; j < 3; j++) {
            p[j]     = fmaf(lv, w_d1[k * 3 + j], p[j]);
            p[3 + j] = fmaf(lv, w_d2[k * 3 + j], p[3 + j]);
        }
    }
    #pragma unroll
    for (int j = 0; j < 6; j++) red[j][t] = p[j];
    __syncthreads();
    for (int s = 128; s > 0; s >>= 1) {
        if (t < s) {
            #pragma unroll
            for (int j = 0; j < 6; j++) red[j][t] += red[j][t + s];
        }
        __syncthreads();
    }
    if (t < 3) {
        lw[t]     = red[t][0] + b_d1[t];
        lw[3 + t] = red[3 + t][0] + b_d2[t];
    }
    __syncthreads();
    float l10 = lw[0], l11 = lw[1], l12 = lw[2];
    float l20 = lw[3], l21 = lw[4], l22 = lw[5];
    float w1a0 = w_d1[1536 + 0], w1a1 = w_d1[1536 + 1], w1a2 = w_d1[1536 + 2];
    float w1b0 = w_d1[1539 + 0], w1b1 = w_d1[1539 + 1], w1b2 = w_d1[1539 + 2];
    float w2a0 = w_d2[1536 + 0], w2a1 = w_d2[1536 + 1], w2a2 = w_d2[1536 + 2];
    float w2b0 = w_d2[1539 + 0], w2b1 = w_d2[1539 + 1], w2b2 = w_d2[1539 + 2];
    float w2c0 = w_d2[1542 + 0], w2c1 = w_d2[1542 + 1], w2c2 = w_d2[1542 + 2];
    {
        int n = sl * 512 + t;
        #pragma unroll
        for (int half = 0; half < 2; half++) {
            int i = n / 46;
            int j = n - i * 46;
            float y0 = fmaf((float)i, 119.f / 90.f, 1.f);
            float y1 = fmaf((float)j, 59.f / 45.f, 1.f);
            float k0 = selu_f(l10 + y0 * w1a0 + y1 * w1b0);
            float k1 = selu_f(l11 + y0 * w1a1 + y1 * w1b1);
            float k2 = selu_f(l12 + y0 * w1a2 + y1 * w1b2);
            float o0 = selu_f(l20 + k0 * w2a0 + k1 * w2b0 + k2 * w2c0);
            float o1 = selu_f(l21 + k0 * w2a1 + k1 * w2b1 + k2 * w2c1);
            float o2 = selu_f(l22 + k0 * w2a2 + k1 * w2b2 + k2 * w2c2);
            size_t pidx = (size_t)(b * 4096 + n) * 3;
            out[pidx + 0] = o0;
            out[pidx + 1] = o1;
            out[pidx + 2] = o2;
            n += 256;
        }
    }
}

// ---------------------------------------------------------------------------
extern "C" void kernel_launch(void* const* d_in, const int* in_sizes, int n_in,
                              void* d_out, int out_size, void* d_ws, size_t ws_size,
                              hipStream_t stream) {
    const float* x    = (const float*)d_in[0];
    const int*   knn  = (const int*)d_in[1];
    const float* w_e1 = (const float*)d_in[2];
    const float* b_e1 = (const float*)d_in[3];
    const float* w_g1 = (const float*)d_in[4];
    const float* b_g1 = (const float*)d_in[5];
    const float* w_g2 = (const float*)d_in[6];
    const float* b_g2 = (const float*)d_in[7];
    const float* w_e2 = (const float*)d_in[8];
    const float* b_e2 = (const float*)d_in[9];
    const float* w_d1 = (const float*)d_in[10];
    const float* b_d1 = (const float*)d_in[11];
    const float* w_d2 = (const float*)d_in[12];
    const float* b_d2 = (const float*)d_in[13];
    float* out = (float*)d_out;

    const int BN = in_sizes[0] / 3;   // 32768
    const int E  = in_sizes[1] / 2;   // 524288
    const int Bb = BN / 4096;         // 8
    const int* src = knn;
    const int* dst = knn + E;

    size_t off = 0;
    auto alloc = [&](size_t bytes) -> void* {
        void* p = (char*)d_ws + off;
        off += (bytes + 255) & ~(size_t)255;
        return p;
    };
    unsigned short* hs1 = (unsigned short*)alloc((size_t)(BN + 1) * 64 * 2);
    unsigned short* hs2 = (unsigned short*)alloc((size_t)(BN + 1) * 128 * 2);
    unsigned short* a1  = (unsigned short*)alloc((size_t)BN * 64 * 2);
    unsigned short* a2  = (unsigned short*)alloc((size_t)BN * 128 * 2);
    unsigned short* Wp1 = (unsigned short*)alloc((size_t)16 * 64 * 8 * 2);
    unsigned short* Wp2 = (unsigned short*)alloc((size_t)128 * 64 * 8 * 2);
    unsigned int* menc = (unsigned int*)alloc((size_t)Bb * 512 * 4);
    float* lat    = (float*)alloc((size_t)Bb * 512 * 4);
    float* dinv   = (float*)alloc((size_t)BN * 4);
    int*   cnt    = (int*)alloc((size_t)BN * 4);
    int*   epos   = (int*)alloc((size_t)E * 4);
    int*   indptr = (int*)alloc((size_t)(BN + 1) * 4);
    int*   bsums  = (int*)alloc((size_t)128 * 4);
    int*   ssrc   = (int*)alloc((size_t)(E + 7 * BN + 1024) * 4);
    (void)ws_size;

    const int nb_scatter = (E + 255) / 256;  // 2048

    // prep: zero cnt + sentinel rows + m_enc, pack both weight matrices
    prep_kernel<<<273, 256, 0, stream>>>(
        cnt, (unsigned int*)(hs1 + (size_t)BN * 64),
        (unsigned int*)(hs2 + (size_t)BN * 128), menc, w_g1, Wp1, w_g2, Wp2);
    // count + per-edge slot
    count_kernel<<<(E + 255) / 256, 256, 0, stream>>>(dst, cnt, epos, E);
    scanA_kernel<<<BN / 256, 256, 0, stream>>>(cnt, bsums, dinv);
    scanC_kernel<<<BN / 256, 256, 0, stream>>>(cnt, bsums, indptr, ssrc, BN);
    // scatter || encoder
    scatter_cov_kernel<<<nb_scatter + 128, 256, 0, stream>>>(
        src, dst, epos, indptr, ssrc, E, nb_scatter,
        x, w_e1, b_e1, dinv, hs1);

    // GCN1 split: agg(64) -> MFMA K=64 -> bf16 hs2 (prescaled)
    agg_kernel<8, 0><<<BN / 32, 256, 0, stream>>>(hs1, dinv, indptr, ssrc, a1, BN);
    gemm1_kernel<<<BN / 128, 256, 0, stream>>>(a1, Wp1, b_g1, dinv, hs2);

    // GCN2 split: agg(128) in TWO channel passes (4.2 MB working set each,
    // fits per-XCD L2) -> MFMA + column max (atomicMax)
    agg_kernel<16, 0><<<BN / 32, 256, 0, stream>>>(hs2, dinv, indptr, ssrc, a2, BN);
    agg_kernel<16, 8><<<BN / 32, 256, 0, stream>>>(hs2, dinv, indptr, ssrc, a2, BN);
    gemm2_kernel<<<dim3(BN / 128, 4), 256, 0, stream>>>(a2, Wp2, b_g2, menc, 512);

    // latent matmul, parallel over 8x16 blocks
    lat_kernel<<<dim3(Bb, 16), 256, 0, stream>>>(menc, w_e2, b_e2, lat);

    // latw + decode (64 blocks: 8 batches x 8 slices)
    latw_decode_kernel<<<Bb * 8, 256, 0, stream>>>(lat, w_d1, b_d1, w_d2, b_d2, out);
}

// Round 14
// 202.866 us; speedup vs baseline: 1.2352x; 1.0107x over previous
//
#include <hip/hip_runtime.h>
#include <math.h>

#define SELU_SCALE 1.0507009873554804934193349852946f
#define SELU_ALPHA 1.6732632423543772848170429916717f

typedef short bf16x8 __attribute__((ext_vector_type(8)));
typedef float f32x4 __attribute__((ext_vector_type(4)));

__device__ __forceinline__ float selu_f(float x) {
    return SELU_SCALE * (x > 0.f ? x : SELU_ALPHA * expm1f(x));
}

__device__ __forceinline__ unsigned short f2bf(float f) {
    unsigned int u = __float_as_uint(f);
    u += 0x7FFF + ((u >> 16) & 1);  // round-to-nearest-even
    return (unsigned short)(u >> 16);
}
__device__ __forceinline__ float bflo(unsigned int u) { return __uint_as_float(u << 16); }
__device__ __forceinline__ float bfhi(unsigned int u) { return __uint_as_float(u & 0xFFFF0000u); }

// monotonic float<->uint encoding (order-preserving); max in uint == max in float
__device__ __forceinline__ unsigned int fenc(float f) {
    unsigned int u = __float_as_uint(f);
    return (u & 0x80000000u) ? ~u : (u | 0x80000000u);
}
__device__ __forceinline__ float fdec(unsigned int u) {
    return __uint_as_float((u & 0x80000000u) ? (u ^ 0x80000000u) : ~u);
}

__device__ __forceinline__ void acc8(float* a, uint4 v) {
    a[0] += bflo(v.x); a[1] += bfhi(v.x);
    a[2] += bflo(v.y); a[3] += bfhi(v.y);
    a[4] += bflo(v.z); a[5] += bfhi(v.z);
    a[6] += bflo(v.w); a[7] += bfhi(v.w);
}

__device__ __forceinline__ uint4 pack8(const float* a, float dv) {
    uint4 pk;
    pk.x = (unsigned int)f2bf(a[0] * dv) | ((unsigned int)f2bf(a[1] * dv) << 16);
    pk.y = (unsigned int)f2bf(a[2] * dv) | ((unsigned int)f2bf(a[3] * dv) << 16);
    pk.z = (unsigned int)f2bf(a[4] * dv) | ((unsigned int)f2bf(a[5] * dv) << 16);
    pk.w = (unsigned int)f2bf(a[6] * dv) | ((unsigned int)f2bf(a[7] * dv) << 16);
    return pk;
}

// ---------------------------------------------------------------------------
// prep: blocks 0..127 zero cnt; block 128 zeros sentinel rows + m_enc;
// blocks 129..272 pack weights into MFMA B-fragment layout.
// ---------------------------------------------------------------------------
__global__ __launch_bounds__(256) void prep_kernel(
    int* __restrict__ cnt, unsigned int* __restrict__ pad1,
    unsigned int* __restrict__ pad2, unsigned int* __restrict__ menc,
    const float* __restrict__ W1, unsigned short* __restrict__ Wp1,
    const float* __restrict__ W2, unsigned short* __restrict__ Wp2) {
    int b = blockIdx.x;
    int t = threadIdx.x;
    if (b < 128) {
        cnt[b * 256 + t] = 0;
    } else if (b == 128) {
        if (t < 32) pad1[t] = 0;   // hs1 sentinel row (64 bf16)
        if (t < 64) pad2[t] = 0;   // hs2 sentinel row (128 bf16)
        for (int i = t; i < 4096; i += 256) menc[i] = 0u;  // enc-min
    } else {
        if (t >= 64) return;
        int fb = b - 129;
        const float* W; unsigned short* Wp; int K, N, f;
        if (fb < 16) { W = W1; Wp = Wp1; K = 64; N = 128; f = fb; }
        else         { W = W2; Wp = Wp2; K = 128; N = 512; f = fb - 16; }
        int l = t;  // 0..63
        int KS = K / 32;
        int nt = f / KS, ks = f % KS;
        int ncol = nt * 16 + (l & 15);
        int k0 = ks * 32 + (l >> 4) * 8;
        unsigned short v[8];
        #pragma unroll
        for (int j = 0; j < 8; j++) v[j] = f2bf(W[(size_t)(k0 + j) * N + ncol]);
        *(uint4*)&Wp[((size_t)f * 64 + l) * 8] = *(uint4*)v;
    }
}

// count degrees AND record each edge's slot within its destination's segment
__global__ void count_kernel(const int* __restrict__ dst, int* __restrict__ cnt,
                             int* __restrict__ epos, int E) {
    int e = blockIdx.x * blockDim.x + threadIdx.x;
    if (e < E) epos[e] = atomicAdd(&cnt[dst[e]], 1);
}

// ---------------------------------------------------------------------------
// padfill: fixed-stride-64 rows — dinv, padded count (cap 64), sentinel-fill
// pad slots.  Replaces the CSR scan entirely.
// ---------------------------------------------------------------------------
__global__ __launch_bounds__(256) void padfill_kernel(
    const int* __restrict__ cnt, float* __restrict__ dinv,
    int* __restrict__ pcnt, int* __restrict__ ssrc, int n) {
    int i = blockIdx.x * 256 + threadIdx.x;
    if (i >= n) return;
    int c = cnt[i];
    dinv[i] = rsqrtf((float)(c + 1));
    int pc = (c + 7) & ~7;
    if (pc > 64) pc = 64;
    pcnt[i] = pc;
    int* row = ssrc + ((size_t)i << 6);
    for (int k = c; k < pc; k++) row[k] = n;  // sentinel zero-row
}

// ---------------------------------------------------------------------------
// scatter (blocks 0..nb_scatter-1) || cov_enc (remaining 128 blocks).
// scatter: fixed-stride row, no indptr indirection.
// ---------------------------------------------------------------------------
__global__ __launch_bounds__(256) void scatter_cov_kernel(
    const int* __restrict__ src, const int* __restrict__ dst,
    const int* __restrict__ epos, int* __restrict__ ssrc, int E, int nb_scatter,
    const float* __restrict__ x, const float* __restrict__ w_e1,
    const float* __restrict__ b_e1, const float* __restrict__ dinv,
    unsigned short* __restrict__ hs1) {
    int t = threadIdx.x;
    if ((int)blockIdx.x < nb_scatter) {
        int e = blockIdx.x * 256 + t;
        if (e < E) {
            int pos = epos[e];
            if (pos < 64) ssrc[((size_t)dst[e] << 6) + pos] = src[e];
        }
        return;
    }
    // ---- cov_enc part ----
    __shared__ float Wl[12 * 64];
    __shared__ float Bl[64];
    __shared__ float xs[280 * 3];
    int cb = blockIdx.x - nb_scatter;  // 0..127
    for (int i = t; i < 768; i += 256) Wl[i] = w_e1[i];
    if (t < 64) Bl[t] = b_e1[t];
    int p0 = cb * 256;
    int n0 = p0 & 4095;
    const float* xb = x + (size_t)(p0 - n0) * 3;  // batch base (256 | 4096)
    for (int idx = t; idx < 840; idx += 256) {
        int slot = idx / 3, d = idx - slot * 3;
        int g = n0 - 12 + slot;
        g = g < 0 ? 0 : (g > 4095 ? 4095 : g);
        xs[idx] = xb[g * 3 + d];
    }
    __syncthreads();
    int p = p0 + t;
    int n = n0 + t;
    int lo = n - 12 < 0 ? 0 : n - 12;
    int hi = n + 12 > 4095 ? 4095 : n + 12;
    int slo = lo - n0 + 12, shi = hi - n0 + 12;
    float sx = 0.f, sy = 0.f, sz = 0.f;
    float sxx = 0.f, sxy = 0.f, sxz = 0.f, syy = 0.f, syz = 0.f, szz = 0.f;
    for (int s = slo; s <= shi; s++) {
        float xv = xs[s * 3 + 0], yv = xs[s * 3 + 1], zv = xs[s * 3 + 2];
        sx += xv; sy += yv; sz += zv;
        sxx = fmaf(xv, xv, sxx); sxy = fmaf(xv, yv, sxy); sxz = fmaf(xv, zv, sxz);
        syy = fmaf(yv, yv, syy); syz = fmaf(yv, zv, syz); szz = fmaf(zv, zv, szz);
    }
    float cntf = (float)(shi - slo + 1);
    float rin = 1.f / cntf;
    float mx = sx * rin, my = sy * rin, mz = sz * rin;
    const float inv23 = 1.f / 23.f;
    float c00 = (sxx - sx * mx) * inv23;
    float c01 = (sxy - sx * my) * inv23;
    float c02 = (sxz - sx * mz) * inv23;
    float c11 = (syy - sy * my) * inv23;
    float c12 = (syz - sy * mz) * inv23;
    float c22 = (szz - sz * mz) * inv23;
    float feat[12];
    feat[0] = xs[(t + 12) * 3 + 0];
    feat[1] = xs[(t + 12) * 3 + 1];
    feat[2] = xs[(t + 12) * 3 + 2];
    feat[3] = c00; feat[4] = c01; feat[5]  = c02;
    feat[6] = c01; feat[7] = c11; feat[8]  = c12;
    feat[9] = c02; feat[10] = c12; feat[11] = c22;
    float dv = dinv[p];
    unsigned int* hp = (unsigned int*)(hs1 + (size_t)p * 64);
    for (int c = 0; c < 64; c += 2) {
        float a0 = Bl[c], a1 = Bl[c + 1];
        #pragma unroll
        for (int i = 0; i < 12; i++) {
            a0 = fmaf(feat[i], Wl[i * 64 + c], a0);
            a1 = fmaf(feat[i], Wl[i * 64 + c + 1], a1);
        }
        unsigned int pk = (unsigned int)f2bf(dv * selu_f(a0)) |
                          ((unsigned int)f2bf(dv * selu_f(a1)) << 16);
        hp[c >> 1] = pk;
    }
}

// ---------------------------------------------------------------------------
// Aggregation (templated C), standalone for max occupancy.  Fixed-stride-64
// rows, 8 channels (uint4) per thread, 8-deep batching, int4 index loads.
// ---------------------------------------------------------------------------
template <int C>
__global__ __launch_bounds__(256) void agg_kernel(
    const unsigned short* __restrict__ hs, const float* __restrict__ dinv,
    const int* __restrict__ pcnt, const int* __restrict__ ssrc,
    unsigned short* __restrict__ out, int n_nodes) {
    constexpr int TPN = C / 8;
    int node = blockIdx.x * (256 / TPN) + threadIdx.x / TPN;
    int cq = threadIdx.x % TPN;
    if (node >= n_nodes) return;
    const uint4* hp = (const uint4*)hs;
    float a[8];
    {
        uint4 u = hp[(size_t)node * TPN + cq];
        a[0] = bflo(u.x); a[1] = bfhi(u.x);
        a[2] = bflo(u.y); a[3] = bfhi(u.y);
        a[4] = bflo(u.z); a[5] = bfhi(u.z);
        a[6] = bflo(u.w); a[7] = bfhi(u.w);
    }
    int pc = pcnt[node];
    const int* sp = ssrc + ((size_t)node << 6);
    for (int j = 0; j < pc; j += 8) {
        int4 sa = *(const int4*)&sp[j];
        int4 sb = *(const int4*)&sp[j + 4];
        uint4 v0 = hp[(size_t)sa.x * TPN + cq];
        uint4 v1 = hp[(size_t)sa.y * TPN + cq];
        uint4 v2 = hp[(size_t)sa.z * TPN + cq];
        uint4 v3 = hp[(size_t)sa.w * TPN + cq];
        uint4 v4 = hp[(size_t)sb.x * TPN + cq];
        uint4 v5 = hp[(size_t)sb.y * TPN + cq];
        uint4 v6 = hp[(size_t)sb.z * TPN + cq];
        uint4 v7 = hp[(size_t)sb.w * TPN + cq];
        acc8(a, v0); acc8(a, v1); acc8(a, v2); acc8(a, v3);
        acc8(a, v4); acc8(a, v5); acc8(a, v6); acc8(a, v7);
    }
    ((uint4*)out)[(size_t)node * TPN + cq] = pack8(a, dinv[node]);
}

// ---------------------------------------------------------------------------
// MFMA bf16 GEMM (K=64, N=128): hs2 = f2bf(dinv*selu(a1 @ W1 + b)).
// ---------------------------------------------------------------------------
__global__ __launch_bounds__(256) void gemm1_kernel(
    const unsigned short* __restrict__ A, const unsigned short* __restrict__ Wp,
    const float* __restrict__ bias, const float* __restrict__ dinv,
    unsigned short* __restrict__ hs2) {
    constexpr int LDA = 72;  // 64 + 8 bf16 pad
    __shared__ unsigned short As[128 * LDA];
    int t = threadIdx.x;
    int R0 = blockIdx.x * 128;

    for (int c = t; c < 128 * 8; c += 256) {
        int row = c >> 3, off = c & 7;
        *(uint4*)&As[row * LDA + off * 8] =
            *(const uint4*)&A[(size_t)(R0 + row) * 64 + off * 8];
    }
    __syncthreads();

    int wave = t >> 6, l = t & 63;
    int ml = l & 15, q = l >> 4;
    int wr = wave * 32;
    f32x4 acc[2][8];
    #pragma unroll
    for (int mf = 0; mf < 2; mf++)
        #pragma unroll
        for (int nf = 0; nf < 8; nf++) acc[mf][nf] = (f32x4){0.f, 0.f, 0.f, 0.f};
    const bf16x8* wp8 = (const bf16x8*)Wp;
    #pragma unroll
    for (int ks = 0; ks < 2; ks++) {
        bf16x8 af[2];
        #pragma unroll
        for (int mf = 0; mf < 2; mf++)
            af[mf] = *(const bf16x8*)&As[(wr + mf * 16 + ml) * LDA + ks * 32 + q * 8];
        bf16x8 bfr[8];
        #pragma unroll
        for (int nf = 0; nf < 8; nf++)
            bfr[nf] = wp8[(size_t)(nf * 2 + ks) * 64 + l];
        #pragma unroll
        for (int mf = 0; mf < 2; mf++)
            #pragma unroll
            for (int nf = 0; nf < 8; nf++)
                acc[mf][nf] = __builtin_amdgcn_mfma_f32_16x16x32_bf16(
                    af[mf], bfr[nf], acc[mf][nf], 0, 0, 0);
    }
    float bj[8];
    #pragma unroll
    for (int nf = 0; nf < 8; nf++) bj[nf] = bias[nf * 16 + ml];
    #pragma unroll
    for (int mf = 0; mf < 2; mf++) {
        #pragma unroll
        for (int r = 0; r < 4; r++) {
            int row = R0 + wr + mf * 16 + q * 4 + r;
            float dv = dinv[row];
            #pragma unroll
            for (int nf = 0; nf < 8; nf++) {
                float v = dv * selu_f(acc[mf][nf][r] + bj[nf]);
                hs2[(size_t)row * 128 + nf * 16 + ml] = f2bf(v);
            }
        }
    }
}

// ---------------------------------------------------------------------------
// MFMA bf16 GEMM (K=128): selu + column max -> atomicMax into m_enc (exact).
// ---------------------------------------------------------------------------
__global__ __launch_bounds__(256) void gemm2_kernel(
    const unsigned short* __restrict__ A, const unsigned short* __restrict__ Wp,
    const float* __restrict__ bias, unsigned int* __restrict__ menc, int Nfull) {
    constexpr int KS = 4;
    constexpr int LDA = 136;  // 128 + 8
    constexpr int CPR = 16;
    __shared__ unsigned short As[128 * LDA];
    int t = threadIdx.x;
    int wave = t >> 6, l = t & 63;
    int ml = l & 15, q = l >> 4;
    int R0 = blockIdx.x * 128;
    int cb = blockIdx.y * 128;

    for (int c = t; c < 128 * CPR; c += 256) {
        int row = c / CPR, off = c % CPR;
        *(uint4*)&As[row * LDA + off * 8] =
            *(const uint4*)&A[(size_t)(R0 + row) * 128 + off * 8];
    }
    __syncthreads();

    f32x4 acc[2][8];
    #pragma unroll
    for (int mf = 0; mf < 2; mf++)
        #pragma unroll
        for (int nf = 0; nf < 8; nf++) acc[mf][nf] = (f32x4){0.f, 0.f, 0.f, 0.f};

    const bf16x8* wp8 = (const bf16x8*)Wp;
    int wr = wave * 32;
    #pragma unroll
    for (int ks = 0; ks < KS; ks++) {
        bf16x8 af[2];
        #pragma unroll
        for (int mf = 0; mf < 2; mf++)
            af[mf] = *(const bf16x8*)&As[(wr + mf * 16 + ml) * LDA + ks * 32 + q * 8];
        bf16x8 bfr[8];
        #pragma unroll
        for (int nf = 0; nf < 8; nf++)
            bfr[nf] = wp8[(size_t)(((cb >> 4) + nf) * KS + ks) * 64 + l];
        #pragma unroll
        for (int mf = 0; mf < 2; mf++)
            #pragma unroll
            for (int nf = 0; nf < 8; nf++)
                acc[mf][nf] = __builtin_amdgcn_mfma_f32_16x16x32_bf16(
                    af[mf], bfr[nf], acc[mf][nf], 0, 0, 0);
    }

    // selu + column max; C/D layout: col = ml, row = q*4 + r
    float cmax[8];
    #pragma unroll
    for (int nf = 0; nf < 8; nf++) {
        float bj = bias[cb + nf * 16 + ml];
        float v = -INFINITY;
        #pragma unroll
        for (int mf = 0; mf < 2; mf++)
            #pragma unroll
            for (int r = 0; r < 4; r++)
                v = fmaxf(v, selu_f(acc[mf][nf][r] + bj));
        v = fmaxf(v, __shfl_xor(v, 16, 64));
        v = fmaxf(v, __shfl_xor(v, 32, 64));
        cmax[nf] = v;
    }
    __syncthreads();  // before reusing As as f32 scratch
    float* redf = (float*)As;  // [4 waves][128 cols]
    if (ml == l) {  // lanes 0..15
        #pragma unroll
        for (int nf = 0; nf < 8; nf++) redf[wave * 128 + nf * 16 + l] = cmax[nf];
    }
    __syncthreads();
    if (t < 128) {
        float v = redf[t];
        v = fmaxf(v, redf[128 + t]);
        v = fmaxf(v, redf[256 + t]);
        v = fmaxf(v, redf[384 + t]);
        int b = blockIdx.x >> 5;  // 32 row-tiles per batch
        atomicMax(&menc[b * 512 + cb + t], fenc(v));
    }
}

// ---------------------------------------------------------------------------
// lat: grid (8 batches, 16 col-groups of 32).  lat[b][c] =
// selu(sum_k m[b][k]*w_e2[k][c] + b_e2[c]).  k split 8 ways, LDS reduce.
// ---------------------------------------------------------------------------
__global__ __launch_bounds__(256) void lat_kernel(
    const unsigned int* __restrict__ menc, const float* __restrict__ w_e2,
    const float* __restrict__ b_e2, float* __restrict__ lat) {
    int b = blockIdx.x;
    int cg = blockIdx.y;
    int t = threadIdx.x;
    __shared__ float ml[512];
    __shared__ float red[8][32];
    ml[t] = fdec(menc[b * 512 + t]);
    ml[t + 256] = fdec(menc[b * 512 + t + 256]);
    __syncthreads();
    int cl = t & 31;          // column within group
    int kg = t >> 5;          // 0..7, k-chunks of 64
    int c = cg * 32 + cl;
    const float* wp = w_e2 + (size_t)(kg * 64) * 512 + c;
    const float* mlp = ml + kg * 64;
    float acc = 0.f;
    #pragma unroll 16
    for (int k = 0; k < 64; k++) acc = fmaf(mlp[k], wp[(size_t)k * 512], acc);
    red[kg][cl] = acc;
    __syncthreads();
    if (t < 32) {
        float v = ((red[0][t] + red[1][t]) + (red[2][t] + red[3][t])) +
                  ((red[4][t] + red[5][t]) + (red[6][t] + red[7][t]));
        lat[b * 512 + cg * 32 + t] = selu_f(v + b_e2[cg * 32 + t]);
    }
}

// ---------------------------------------------------------------------------
// latw + decode: 64 blocks = 8 batches x 8 point-slices.  Each block
// recomputes the tiny latw reduction (512x6) then decodes its 512 points.
// ---------------------------------------------------------------------------
__global__ __launch_bounds__(256) void latw_decode_kernel(
    const float* __restrict__ lat, const float* __restrict__ w_d1,
    const float* __restrict__ b_d1, const float* __restrict__ w_d2,
    const float* __restrict__ b_d2, float* __restrict__ out) {
    int b = blockIdx.x >> 3;   // batch
    int sl = blockIdx.x & 7;   // point slice
    int t = threadIdx.x;
    __shared__ float ll[512];
    __shared__ float red[6][256];
    __shared__ float lw[6];
    ll[t] = lat[b * 512 + t];
    ll[t + 256] = lat[b * 512 + t + 256];
    __syncthreads();
    float p[6] = {0.f, 0.f, 0.f, 0.f, 0.f, 0.f};
    for (int k = t; k < 512; k += 256) {
        float lv = ll[k];
        #pragma unroll
        for (int j = 0; j < 3; j++) {
            p[j]     = fmaf(lv, w_d1[k * 3 + j], p[j]);
            p[3 + j] = fmaf(lv, w_d2[k * 3 + j], p[3 + j]);
        }
    }
    #pragma unroll
    for (int j = 0; j < 6; j++) red[j][t] = p[j];
    __syncthreads();
    for (int s = 128; s > 0; s >>= 1) {
        if (t < s) {
            #pragma unroll
            for (int j = 0; j < 6; j++) red[j][t] += red[j][t + s];
        }
        __syncthreads();
    }
    if (t < 3) {
        lw[t]     = red[t][0] + b_d1[t];
        lw[3 + t] = red[3 + t][0] + b_d2[t];
    }
    __syncthreads();
    float l10 = lw[0], l11 = lw[1], l12 = lw[2];
    float l20 = lw[3], l21 = lw[4], l22 = lw[5];
    float w1a0 = w_d1[1536 + 0], w1a1 = w_d1[1536 + 1], w1a2 = w_d1[1536 + 2];
    float w1b0 = w_d1[1539 + 0], w1b1 = w_d1[1539 + 1], w1b2 = w_d1[1539 + 2];
    float w2a0 = w_d2[1536 + 0], w2a1 = w_d2[1536 + 1], w2a2 = w_d2[1536 + 2];
    float w2b0 = w_d2[1539 + 0], w2b1 = w_d2[1539 + 1], w2b2 = w_d2[1539 + 2];
    float w2c0 = w_d2[1542 + 0], w2c1 = w_d2[1542 + 1], w2c2 = w_d2[1542 + 2];
    {
        int n = sl * 512 + t;
        #pragma unroll
        for (int half = 0; half < 2; half++) {
            int i = n / 46;
            int j = n - i * 46;
            float y0 = fmaf((float)i, 119.f / 90.f, 1.f);
            float y1 = fmaf((float)j, 59.f / 45.f, 1.f);
            float k0 = selu_f(l10 + y0 * w1a0 + y1 * w1b0);
            float k1 = selu_f(l11 + y0 * w1a1 + y1 * w1b1);
            float k2 = selu_f(l12 + y0 * w1a2 + y1 * w1b2);
            float o0 = selu_f(l20 + k0 * w2a0 + k1 * w2b0 + k2 * w2c0);
            float o1 = selu_f(l21 + k0 * w2a1 + k1 * w2b1 + k2 * w2c1);
            float o2 = selu_f(l22 + k0 * w2a2 + k1 * w2b2 + k2 * w2c2);
            size_t pidx = (size_t)(b * 4096 + n) * 3;
            out[pidx + 0] = o0;
            out[pidx + 1] = o1;
            out[pidx + 2] = o2;
            n += 256;
        }
    }
}

// ---------------------------------------------------------------------------
extern "C" void kernel_launch(void* const* d_in, const int* in_sizes, int n_in,
                              void* d_out, int out_size, void* d_ws, size_t ws_size,
                              hipStream_t stream) {
    const float* x    = (const float*)d_in[0];
    const int*   knn  = (const int*)d_in[1];
    const float* w_e1 = (const float*)d_in[2];
    const float* b_e1 = (const float*)d_in[3];
    const float* w_g1 = (const float*)d_in[4];
    const float* b_g1 = (const float*)d_in[5];
    const float* w_g2 = (const float*)d_in[6];
    const float* b_g2 = (const float*)d_in[7];
    const float* w_e2 = (const float*)d_in[8];
    const float* b_e2 = (const float*)d_in[9];
    const float* w_d1 = (const float*)d_in[10];
    const float* b_d1 = (const float*)d_in[11];
    const float* w_d2 = (const float*)d_in[12];
    const float* b_d2 = (const float*)d_in[13];
    float* out = (float*)d_out;

    const int BN = in_sizes[0] / 3;   // 32768
    const int E  = in_sizes[1] / 2;   // 524288
    const int Bb = BN / 4096;         // 8
    const int* src = knn;
    const int* dst = knn + E;

    size_t off = 0;
    auto alloc = [&](size_t bytes) -> void* {
        void* p = (char*)d_ws + off;
        off += (bytes + 255) & ~(size_t)255;
        return p;
    };
    unsigned short* hs1 = (unsigned short*)alloc((size_t)(BN + 1) * 64 * 2);
    unsigned short* hs2 = (unsigned short*)alloc((size_t)(BN + 1) * 128 * 2);
    unsigned short* a1  = (unsigned short*)alloc((size_t)BN * 64 * 2);
    unsigned short* a2  = (unsigned short*)alloc((size_t)BN * 128 * 2);
    unsigned short* Wp1 = (unsigned short*)alloc((size_t)16 * 64 * 8 * 2);
    unsigned short* Wp2 = (unsigned short*)alloc((size_t)128 * 64 * 8 * 2);
    unsigned int* menc = (unsigned int*)alloc((size_t)Bb * 512 * 4);
    float* lat    = (float*)alloc((size_t)Bb * 512 * 4);
    float* dinv   = (float*)alloc((size_t)BN * 4);
    int*   cnt    = (int*)alloc((size_t)BN * 4);
    int*   pcnt   = (int*)alloc((size_t)BN * 4);
    int*   epos   = (int*)alloc((size_t)E * 4);
    int*   ssrc   = (int*)alloc((size_t)BN * 64 * 4);
    (void)ws_size;

    const int nb_scatter = (E + 255) / 256;  // 2048

    // prep: zero cnt + sentinel rows + m_enc, pack both weight matrices
    prep_kernel<<<273, 256, 0, stream>>>(
        cnt, (unsigned int*)(hs1 + (size_t)BN * 64),
        (unsigned int*)(hs2 + (size_t)BN * 128), menc, w_g1, Wp1, w_g2, Wp2);
    // count + per-edge slot
    count_kernel<<<(E + 255) / 256, 256, 0, stream>>>(dst, cnt, epos, E);
    // dinv + padded counts + sentinel pad-fill (replaces CSR scans)
    padfill_kernel<<<BN / 256, 256, 0, stream>>>(cnt, dinv, pcnt, ssrc, BN);
    // scatter || encoder
    scatter_cov_kernel<<<nb_scatter + 128, 256, 0, stream>>>(
        src, dst, epos, ssrc, E, nb_scatter, x, w_e1, b_e1, dinv, hs1);

    // GCN1 split: agg(64) -> MFMA K=64 -> bf16 hs2 (prescaled)
    agg_kernel<64><<<BN / 32, 256, 0, stream>>>(hs1, dinv, pcnt, ssrc, a1, BN);
    gemm1_kernel<<<BN / 128, 256, 0, stream>>>(a1, Wp1, b_g1, dinv, hs2);

    // GCN2 split: agg(128) -> MFMA + column max (atomicMax)
    agg_kernel<128><<<BN / 16, 256, 0, stream>>>(hs2, dinv, pcnt, ssrc, a2, BN);
    gemm2_kernel<<<dim3(BN / 128, 4), 256, 0, stream>>>(a2, Wp2, b_g2, menc, 512);

    // latent matmul, parallel over 8x16 blocks
    lat_kernel<<<dim3(Bb, 16), 256, 0, stream>>>(menc, w_e2, b_e2, lat);

    // latw + decode (64 blocks: 8 batches x 8 slices)
    latw_decode_kernel<<<Bb * 8, 256, 0, stream>>>(lat, w_d1, b_d1, w_d2, b_d2, out);
}